// Round 4
// baseline (677.473 us; speedup 1.0000x reference)
//
#include <hip/hip_runtime.h>
#include <hip/hip_bf16.h>
#include <hip/hip_cooperative_groups.h>

namespace cg = cooperative_groups;

#define N_NODES   100000
#define N_EDGES   1600000
#define N_ETYPES  3
#define IN_FEATS  128
#define HEADS     4
#define OUT_FEATS 16
#define EDGE_FEATS 64
#define HD        64            // HEADS*OUT_FEATS
#define NEG_SLOPE 0.2f
#define MAXD_LDS  128           // agg fast-path max degree (Poisson(16): P(>128)~0)

#define NBUCK     800           // buckets for counting sort
#define NPB       125           // nodes per bucket (800*125 = N_NODES)
#define PBLK      400           // blocks in hist/scatter phases
#define EPB       4000          // edges per block (400*4000 = N_EDGES)
#define BCAP      2560          // LDS stage capacity in csr phase (mean 2000, std ~45)

// packed edge payload: src(17b) | ty(2b)<<17 | ldst(7b)<<19  — 26 bits.
// original edge index NOT stored: a_out is rebuilt in original order.

typedef short s16x8 __attribute__((ext_vector_type(8)));
typedef float f32x4 __attribute__((ext_vector_type(4)));

__device__ __forceinline__ short f2bs(float f) {
    __hip_bfloat16 h = __float2bfloat16(f);
    return *reinterpret_cast<short*>(&h);
}

// ---------------------------------------------------------------------------
// Kernel A (MFMA): feat = x @ W, bf16 store, fused el/er.
// W->bf16^T conversion is done per-block in LDS (W is 32KB, L2-resident).
// Block 6250 computes ee[t,h] (12 scalars) instead — wt_prep and ee_kernel
// launches are eliminated.
// ---------------------------------------------------------------------------
#define XS_STRIDE 136   // 128 + 8 pad shorts
__global__ __launch_bounds__(256) void feat_el_er_kernel(
    const float* __restrict__ x,
    const float* __restrict__ W,
    const float* __restrict__ attn_l,
    const float* __restrict__ attn_r,
    const float* __restrict__ edge_emb,
    const float* __restrict__ W_e,
    const float* __restrict__ attn_e,
    __hip_bfloat16* __restrict__ featb,
    float* __restrict__ el,
    float* __restrict__ eriz,
    float* __restrict__ ee)
{
    const int t = threadIdx.x;

    if (blockIdx.x == N_NODES / 16) {
        // ---- ee block: 12 (ty,h) jobs over 4 waves ----
        const int wv = t >> 6, e = t & 63;
        for (int j = wv; j < N_ETYPES * HEADS; j += 4) {
            const int ty = j >> 2, h = j & 3;
            float ef = 0.f;
#pragma unroll
            for (int k = 0; k < EDGE_FEATS; ++k)
                ef += edge_emb[ty * EDGE_FEATS + k] *
                      W_e[k * (HEADS * EDGE_FEATS) + h * EDGE_FEATS + e];
            float v = ef * attn_e[h * EDGE_FEATS + e];
#pragma unroll
            for (int m = 1; m < 64; m <<= 1) v += __shfl_xor(v, m, 64);
            if (e == 0) ee[ty * HEADS + h] = v;
        }
        return;
    }

    __shared__ short Xs[16 * XS_STRIDE];
    __shared__ short Ws[64 * XS_STRIDE];

    const int row0 = blockIdx.x * 16;
    {   // stage x -> bf16 LDS
        const int r = t >> 4, k0 = (t & 15) * 8;
        const float4* xg = (const float4*)(x + (size_t)(row0 + r) * IN_FEATS + k0);
        const float4 v0 = xg[0], v1 = xg[1];
        s16x8 p;
        p[0] = f2bs(v0.x); p[1] = f2bs(v0.y); p[2] = f2bs(v0.z); p[3] = f2bs(v0.w);
        p[4] = f2bs(v1.x); p[5] = f2bs(v1.y); p[6] = f2bs(v1.z); p[7] = f2bs(v1.w);
        *(s16x8*)&Xs[r * XS_STRIDE + k0] = p;
    }
    {   // stage W -> bf16 transposed LDS: Ws[n][k] = W[k][n]
        const int n  = t & 63;
        const int kb = (t >> 6) * 32;
#pragma unroll
        for (int kk = 0; kk < 32; kk += 8) {
            s16x8 p;
#pragma unroll
            for (int j = 0; j < 8; ++j)
                p[j] = f2bs(W[(size_t)(kb + kk + j) * HD + n]);   // coalesced over n
            *(s16x8*)&Ws[n * XS_STRIDE + kb + kk] = p;
        }
    }
    __syncthreads();

    const int w    = t >> 6;
    const int lane = t & 63;
    const int m    = lane & 15;
    const int q    = lane >> 4;

    f32x4 acc = {0.f, 0.f, 0.f, 0.f};
#pragma unroll
    for (int kb = 0; kb < 4; ++kb) {
        const s16x8 af = *(const s16x8*)&Xs[m * XS_STRIDE + kb * 32 + q * 8];
        const s16x8 bf = *(const s16x8*)&Ws[(w * 16 + m) * XS_STRIDE + kb * 32 + q * 8];
        acc = __builtin_amdgcn_mfma_f32_16x16x32_bf16(af, bf, acc, 0, 0, 0);
    }

    const float al = attn_l[w * OUT_FEATS + m];
    const float ar = attn_r[w * OUT_FEATS + m];
#pragma unroll
    for (int r = 0; r < 4; ++r) {
        const int row = row0 + q * 4 + r;
        featb[(size_t)row * HD + w * 16 + m] = __float2bfloat16(acc[r]);
        float cl = acc[r] * al;
        float cr = acc[r] * ar;
#pragma unroll
        for (int msk = 1; msk < 16; msk <<= 1) {
            cl += __shfl_xor(cl, msk, 64);
            cr += __shfl_xor(cr, msk, 64);
        }
        if (m == 0) {
            el[row * HEADS + w] = cl;
            eriz[(size_t)row * 8 + w] = cr;
        }
    }
}

// ---------------------------------------------------------------------------
// Cooperative CSR build: hist + scan1 + scan2 + scatter + csr in ONE launch.
// 800 blocks x 256 threads, grid.sync() between phases. LDS is a phase union.
// Replaces 5 separate kernel launches.
// ---------------------------------------------------------------------------
__global__ __launch_bounds__(256, 4) void coop_sort_kernel(
    const int* __restrict__ src, const int* __restrict__ dst,
    const int* __restrict__ etype,
    int* __restrict__ bhist, int* __restrict__ btot, int* __restrict__ bbase,
    int* __restrict__ ptr, int* __restrict__ sc_bucket, int* __restrict__ sc_csr)
{
    cg::grid_group grid = cg::this_grid();
    __shared__ int smem[BCAP + 256];   // 11.25 KB union over phases
    const int t = threadIdx.x, b = blockIdx.x;

    // ---- phase A: per-block bucket histogram (blocks < PBLK) ----
    if (b < PBLK) {
        int* h = smem;                               // NBUCK ints
        for (int j = t; j < NBUCK; j += 256) h[j] = 0;
        __syncthreads();
        const int e0 = b * EPB;
        for (int i = t; i < EPB; i += 256)
            atomicAdd(&h[dst[e0 + i] / NPB], 1);
        __syncthreads();
        for (int j = t; j < NBUCK; j += 256) bhist[b * NBUCK + j] = h[j];
    }
    grid.sync();

    // ---- phase B: per bucket j=b, exclusive scan over PBLK blocks ----
    {
        int* sh = smem;                              // PBLK ints
        const int j = b;
        const int j0 = t, j1 = t + 256;
        int o0 = 0, o1 = 0;
        if (j0 < PBLK) { o0 = bhist[j0 * NBUCK + j]; sh[j0] = o0; }
        if (j1 < PBLK) { o1 = bhist[j1 * NBUCK + j]; sh[j1] = o1; }
        __syncthreads();
        for (int off = 1; off < PBLK; off <<= 1) {
            int v0 = (j0 >= off && j0 < PBLK) ? sh[j0 - off] : 0;
            int v1 = (j1 >= off && j1 < PBLK) ? sh[j1 - off] : 0;
            __syncthreads();
            if (j0 < PBLK) sh[j0] += v0;
            if (j1 < PBLK) sh[j1] += v1;
            __syncthreads();
        }
        if (j0 < PBLK) bhist[j0 * NBUCK + j] = sh[j0] - o0;
        if (j1 < PBLK) bhist[j1 * NBUCK + j] = sh[j1] - o1;
        if (t == 255) btot[j] = sh[PBLK - 1];
    }
    grid.sync();

    // ---- phase C: block 0 scans btot[NBUCK] -> bbase (4 elems/thread) ----
    if (b == 0) {
        int e0 = 0, e1 = 0, e2 = 0, e3 = 0;
        if (t < NBUCK / 4) {
            e0 = btot[4 * t];     e1 = btot[4 * t + 1];
            e2 = btot[4 * t + 2]; e3 = btot[4 * t + 3];
        }
        const int tsum = e0 + e1 + e2 + e3;
        int* sh = smem;
        sh[t] = tsum;
        __syncthreads();
        for (int off = 1; off < 256; off <<= 1) {
            const int v = (t >= off) ? sh[t - off] : 0;
            __syncthreads();
            sh[t] += v;
            __syncthreads();
        }
        const int excl = sh[t] - tsum;
        if (t < NBUCK / 4) {
            bbase[4 * t]     = excl;
            bbase[4 * t + 1] = excl + e0;
            bbase[4 * t + 2] = excl + e0 + e1;
            bbase[4 * t + 3] = excl + e0 + e1 + e2;
        }
        if (t == 255) bbase[NBUCK] = sh[255];
    }
    grid.sync();

    // ---- phase D: scatter into bucket regions (blocks < PBLK) ----
    if (b < PBLK) {
        int* cnt = smem;                             // NBUCK ints
        for (int j = t; j < NBUCK; j += 256)
            cnt[j] = bbase[j] + bhist[b * NBUCK + j];
        __syncthreads();
        const int e0 = b * EPB;
        for (int i = t; i < EPB; i += 256) {
            const int e  = e0 + i;
            const int dn = dst[e];
            const int bu = dn / NPB;
            const int ld = dn - bu * NPB;
            const int slot = atomicAdd(&cnt[bu], 1);
            sc_bucket[slot] = src[e] | (etype[e] << 17) | (ld << 19);
        }
    }
    grid.sync();

    // ---- phase E: per-bucket CSR finalize (bucket = b) ----
    {
        int* sbuf = smem;                            // BCAP
        int* sdeg = smem + BCAP;                     // 128
        int* scur = smem + BCAP + 128;               // 128
        const int lo = bbase[b];
        const int count = bbase[b + 1] - lo;
        const bool staged = (count <= BCAP);

        if (t < 128) sdeg[t] = 0;
        __syncthreads();
        if (staged) {
            for (int i = t; i < count; i += 256) {
                const int v = sc_bucket[lo + i];
                sbuf[i] = v;
                atomicAdd(&sdeg[(v >> 19) & 0x7F], 1);
            }
        } else {
            for (int i = t; i < count; i += 256)
                atomicAdd(&sdeg[(sc_bucket[lo + i] >> 19) & 0x7F], 1);
        }
        __syncthreads();
        const int orig = (t < 128) ? sdeg[t] : 0;
        for (int off = 1; off < 128; off <<= 1) {
            const int v = (t < 128 && t >= off) ? sdeg[t - off] : 0;
            __syncthreads();
            if (t < 128) sdeg[t] += v;
            __syncthreads();
        }
        if (t < 128) {
            const int excl = sdeg[t] - orig;
            if (t < NPB) ptr[b * NPB + t] = lo + excl;
            scur[t] = lo + excl;
        }
        if (b == 0 && t == 0) ptr[N_NODES] = N_EDGES;
        __syncthreads();
        if (staged) {
            for (int i = t; i < count; i += 256) {
                const int v = sbuf[i];
                const int ld = (v >> 19) & 0x7F;
                const int slot = atomicAdd(&scur[ld], 1);
                sc_csr[slot] = v & 0x7FFFF;          // src | ty<<17
            }
        } else {
            for (int i = t; i < count; i += 256) {
                const int v = sc_bucket[lo + i];
                const int ld = (v >> 19) & 0x7F;
                const int slot = atomicAdd(&scur[ld], 1);
                sc_csr[slot] = v & 0x7FFFF;
            }
        }
    }
}

// ---------------------------------------------------------------------------
// Kernel C: per-dst aggregation, one wave per node, two in-wave phases.
// Phase 1: 1 lane per (edge,head): exp ONCE per (e,h); w,src -> LDS; z reduce.
// Phase 2: 8 edges x 8 lanes, 16B dwordx4 feat loads, w broadcast from LDS.
// invz written into eriz[n*8+4..7] (shares cacheline with er for attn_out).
// ---------------------------------------------------------------------------
__global__ __launch_bounds__(256) void agg_kernel(
    const int* __restrict__ sc_csr, const int* __restrict__ ptr,
    const float* __restrict__ el, float* __restrict__ eriz,
    const float* __restrict__ ee, const __hip_bfloat16* __restrict__ featb,
    float* __restrict__ rst)
{
    __shared__ float w_lds[4][MAXD_LDS * HEADS];   // 8 KB
    __shared__ int   s_lds[4][MAXD_LDS];           // 2 KB
    const int wid  = threadIdx.x >> 6;
    const int lane = threadIdx.x & 63;
    const int n    = blockIdx.x * 4 + wid;

    const int p0  = ptr[n];
    const int deg = ptr[n + 1] - p0;
    float* wl = w_lds[wid];
    int*   sl = s_lds[wid];
    const ushort* fb = (const ushort*)featb;

    if (deg <= MAXD_LDS) {
        // ---- phase 1: weights, one lane per (edge, head) ----
        const int eo = lane >> 2;          // edge in group of 16
        const int hA = lane & 3;           // head
        const float er_n = eriz[(size_t)n * 8 + hA];
        const float g0 = ee[hA], g1 = ee[HEADS + hA], g2 = ee[2 * HEADS + hA];

        float zacc = 0.f;
        for (int i0 = 0; i0 < deg; i0 += 16) {
            const int idx = i0 + eo;
            if (idx < deg) {
                const int v  = sc_csr[p0 + idx];
                const int sn = v & 0x1FFFF;
                const int ty = v >> 17;
                float s = el[sn * HEADS + hA] + er_n +
                          ((ty == 0) ? g0 : ((ty == 1) ? g1 : g2));
                s = s > 0.f ? s : NEG_SLOPE * s;
                const float w = __expf(s);
                wl[idx * HEADS + hA] = w;
                if (hA == 0) sl[idx] = sn;
                zacc += w;
            }
        }
        // reduce z over edge groups (lane bits 2..5); lane then holds z[lane&3]
        zacc += __shfl_xor(zacc, 4, 64);
        zacc += __shfl_xor(zacc, 8, 64);
        zacc += __shfl_xor(zacc, 16, 64);
        zacc += __shfl_xor(zacc, 32, 64);
        if (lane < 4)
            eriz[(size_t)n * 8 + 4 + lane] = (deg > 0) ? __frcp_rn(zacc) : 0.f;

        // ---- phase 2: accumulate, 8 edges x 8 lanes, 16B loads ----
        const int q8 = lane >> 3;          // edge slot 0..7
        const int c8 = lane & 7;           // col group: cols 8*c8 .. 8*c8+7
        const int h8 = c8 >> 1;            // head of those cols
        const float inv_z = (deg > 0) ? __frcp_rn(__shfl(zacc, h8, 64)) : 0.f;

        float a0 = 0.f, a1 = 0.f, a2 = 0.f, a3 = 0.f;
        float a4 = 0.f, a5 = 0.f, a6 = 0.f, a7 = 0.f;
        int i = 0;
        for (; i + 8 <= deg; i += 8) {
            const int idx = i + q8;
            const int sA = sl[idx];
            const float wA = wl[idx * HEADS + h8];
            const uint4 fA = *(const uint4*)(fb + ((size_t)sA << 6) + (c8 << 3));
            a0 += __uint_as_float(fA.x << 16) * wA;
            a1 += __uint_as_float(fA.x & 0xFFFF0000u) * wA;
            a2 += __uint_as_float(fA.y << 16) * wA;
            a3 += __uint_as_float(fA.y & 0xFFFF0000u) * wA;
            a4 += __uint_as_float(fA.z << 16) * wA;
            a5 += __uint_as_float(fA.z & 0xFFFF0000u) * wA;
            a6 += __uint_as_float(fA.w << 16) * wA;
            a7 += __uint_as_float(fA.w & 0xFFFF0000u) * wA;
        }
        if (i + q8 < deg) {                // tail (<8 edges), one guarded step
            const int idx = i + q8;
            const int sA = sl[idx];
            const float wA = wl[idx * HEADS + h8];
            const uint4 fA = *(const uint4*)(fb + ((size_t)sA << 6) + (c8 << 3));
            a0 += __uint_as_float(fA.x << 16) * wA;
            a1 += __uint_as_float(fA.x & 0xFFFF0000u) * wA;
            a2 += __uint_as_float(fA.y << 16) * wA;
            a3 += __uint_as_float(fA.y & 0xFFFF0000u) * wA;
            a4 += __uint_as_float(fA.z << 16) * wA;
            a5 += __uint_as_float(fA.z & 0xFFFF0000u) * wA;
            a6 += __uint_as_float(fA.w << 16) * wA;
            a7 += __uint_as_float(fA.w & 0xFFFF0000u) * wA;
        }
        // reduce over the 8 edge slots (lane bits 3..5)
        a0 += __shfl_xor(a0, 8, 64); a0 += __shfl_xor(a0, 16, 64); a0 += __shfl_xor(a0, 32, 64);
        a1 += __shfl_xor(a1, 8, 64); a1 += __shfl_xor(a1, 16, 64); a1 += __shfl_xor(a1, 32, 64);
        a2 += __shfl_xor(a2, 8, 64); a2 += __shfl_xor(a2, 16, 64); a2 += __shfl_xor(a2, 32, 64);
        a3 += __shfl_xor(a3, 8, 64); a3 += __shfl_xor(a3, 16, 64); a3 += __shfl_xor(a3, 32, 64);
        a4 += __shfl_xor(a4, 8, 64); a4 += __shfl_xor(a4, 16, 64); a4 += __shfl_xor(a4, 32, 64);
        a5 += __shfl_xor(a5, 8, 64); a5 += __shfl_xor(a5, 16, 64); a5 += __shfl_xor(a5, 32, 64);
        a6 += __shfl_xor(a6, 8, 64); a6 += __shfl_xor(a6, 16, 64); a6 += __shfl_xor(a6, 32, 64);
        a7 += __shfl_xor(a7, 8, 64); a7 += __shfl_xor(a7, 16, 64); a7 += __shfl_xor(a7, 32, 64);
        if (q8 == 0) {
            f32x4 v0 = {a0 * inv_z, a1 * inv_z, a2 * inv_z, a3 * inv_z};
            f32x4 v1 = {a4 * inv_z, a5 * inv_z, a6 * inv_z, a7 * inv_z};
            *(f32x4*)(rst + (size_t)n * HD + (c8 << 3))     = v0;
            *(f32x4*)(rst + (size_t)n * HD + (c8 << 3) + 4) = v1;
        }
    } else {
        // ---- rare big-degree path: two passes, recompute ----
        const int hA = lane & 3;
        const int eo = lane >> 2;
        const float er_nA = eriz[(size_t)n * 8 + hA];
        const float a0 = ee[hA], a1 = ee[HEADS + hA], a2 = ee[2 * HEADS + hA];
        float zacc = 0.f;
        for (int base = 0; base < deg; base += 16) {
            const int idx = base + eo;
            if (idx < deg) {
                const int v  = sc_csr[p0 + idx];
                const int sn = v & 0x1FFFF;
                const int ty = v >> 17;
                float s = el[sn * HEADS + hA] + er_nA + ((ty == 0) ? a0 : ((ty == 1) ? a1 : a2));
                s = s > 0.f ? s : NEG_SLOPE * s;
                zacc += __expf(s);
            }
        }
#pragma unroll
        for (int m = 4; m < 64; m <<= 1) zacc += __shfl_xor(zacc, m, 64);
        if (lane < 4) eriz[(size_t)n * 8 + 4 + lane] = __frcp_rn(zacc);
        const int h = lane >> 4;
        const float inv_z = __frcp_rn(__shfl(zacc, h, 64));
        const float er_n = eriz[(size_t)n * 8 + h];
        const float g0 = ee[h], g1 = ee[HEADS + h], g2 = ee[2 * HEADS + h];
        float racc = 0.f;
        for (int i = 0; i < deg; ++i) {
            const int v  = sc_csr[p0 + i];
            const int sn = v & 0x1FFFF;
            const int ty = v >> 17;
            float s = el[sn * HEADS + h] + er_n + ((ty == 0) ? g0 : ((ty == 1) ? g1 : g2));
            s = s > 0.f ? s : NEG_SLOPE * s;
            const float a = __expf(s) * inv_z;
            racc += __bfloat162float(featb[(size_t)sn * HD + lane]) * a;
        }
        rst[(size_t)n * HD + lane] = racc;
    }
}

// ---------------------------------------------------------------------------
// Kernel D: a_out in ORIGINAL edge order — fully coalesced float4 writes.
// er+invz share one 32B cacheline per node (eriz).
// ---------------------------------------------------------------------------
__global__ __launch_bounds__(256) void attn_out_kernel(
    const int* __restrict__ src, const int* __restrict__ dst,
    const int* __restrict__ etype,
    const float* __restrict__ el, const float* __restrict__ eriz,
    const float* __restrict__ ee,
    float* __restrict__ a_out)
{
    const int e = blockIdx.x * 256 + threadIdx.x;   // grid exact: E/256
    const int sN = src[e];
    const int dN = dst[e];
    const int ty = etype[e];
    const float4 l4 = *(const float4*)(el + (size_t)sN * HEADS);
    const float4 r4 = *(const float4*)(eriz + (size_t)dN * 8);
    const float4 iz = *(const float4*)(eriz + (size_t)dN * 8 + 4);
    const float4 g4 = *(const float4*)(ee + (size_t)ty * HEADS);
    float4 a;
    float s;
    s = l4.x + r4.x + g4.x; s = s > 0.f ? s : NEG_SLOPE * s; a.x = __expf(s) * iz.x;
    s = l4.y + r4.y + g4.y; s = s > 0.f ? s : NEG_SLOPE * s; a.y = __expf(s) * iz.y;
    s = l4.z + r4.z + g4.z; s = s > 0.f ? s : NEG_SLOPE * s; a.z = __expf(s) * iz.z;
    s = l4.w + r4.w + g4.w; s = s > 0.f ? s : NEG_SLOPE * s; a.w = __expf(s) * iz.w;
    *(float4*)(a_out + (size_t)e * HEADS) = a;
}

extern "C" void kernel_launch(void* const* d_in, const int* in_sizes, int n_in,
                              void* d_out, int out_size, void* d_ws, size_t ws_size,
                              hipStream_t stream)
{
    const float* x        = (const float*)d_in[0];
    const float* W        = (const float*)d_in[1];
    const float* W_e      = (const float*)d_in[2];
    const float* attn_l   = (const float*)d_in[3];
    const float* attn_r   = (const float*)d_in[4];
    const float* attn_e   = (const float*)d_in[5];
    const float* edge_emb = (const float*)d_in[6];
    const int* src   = (const int*)d_in[7];
    const int* dst   = (const int*)d_in[8];
    const int* etype = (const int*)d_in[9];

    float* out     = (float*)d_out;
    float* rst_out = out;                              // N*H*D
    float* a_out   = out + (size_t)N_NODES * HD;       // E*H

    char* w = (char*)d_ws;
    __hip_bfloat16* featb = (__hip_bfloat16*)w; w += (size_t)N_NODES * HD * 2;   // 12.8 MB
    float* el    = (float*)w;  w += (size_t)N_NODES * HEADS * 4;    //  1.6 MB
    float* eriz  = (float*)w;  w += (size_t)N_NODES * 8 * 4;        //  3.2 MB (er|invz)
    float* ee    = (float*)w;  w += 64;
    int*   ptr   = (int*)w;    w += (size_t)(N_NODES + 4) * 4;      //  0.4 MB
    int*   bhist = (int*)w;    w += (size_t)PBLK * NBUCK * 4;       //  1.28 MB
    int*   btot  = (int*)w;    w += (size_t)NBUCK * 4;
    int*   bbase = (int*)w;    w += (size_t)(NBUCK + 4) * 4;
    int*   sc_bucket = (int*)w; w += (size_t)N_EDGES * 4;           //  6.4 MB
    int*   sc_csr    = (int*)w; w += (size_t)N_EDGES * 4;           //  6.4 MB
    // total ~32 MB

    // 1) GEMM + el/er + ee (inline W conversion; +1 block for ee)
    feat_el_er_kernel<<<N_NODES / 16 + 1, 256, 0, stream>>>(
        x, W, attn_l, attn_r, edge_emb, W_e, attn_e, featb, el, eriz, ee);

    // 2) entire CSR build in one cooperative launch (5 kernels -> 1)
    {
        void* cargs[] = {
            (void*)&src, (void*)&dst, (void*)&etype,
            (void*)&bhist, (void*)&btot, (void*)&bbase,
            (void*)&ptr, (void*)&sc_bucket, (void*)&sc_csr
        };
        hipLaunchCooperativeKernel((const void*)coop_sort_kernel,
                                   dim3(NBUCK), dim3(256), cargs, 0, stream);
    }

    // 3) aggregation
    agg_kernel<<<N_NODES / 4, 256, 0, stream>>>(
        sc_csr, ptr, el, eriz, ee, featb, rst_out);

    // 4) attention weights in original edge order
    attn_out_kernel<<<N_EDGES / 256, 256, 0, stream>>>(
        src, dst, etype, el, eriz, ee, a_out);
}

// Round 5
// 279.311 us; speedup vs baseline: 2.4255x; 2.4255x over previous
//
#include <hip/hip_runtime.h>
#include <hip/hip_bf16.h>

#define N_NODES   100000
#define N_EDGES   1600000
#define N_ETYPES  3
#define IN_FEATS  128
#define HEADS     4
#define OUT_FEATS 16
#define EDGE_FEATS 64
#define HD        64            // HEADS*OUT_FEATS
#define NEG_SLOPE 0.2f
#define MAXD_LDS  128           // agg fast-path max degree (Poisson(16): P(>128)~0)

#define NBUCK     800           // buckets for counting sort
#define NPB       125           // nodes per bucket (800*125 = N_NODES)
#define PBLK      400           // blocks in scatter pass
#define EPB       4000          // edges per block (400*4000 = N_EDGES)
#define BCAP      2560          // fixed bucket-region capacity AND LDS stage cap
                                // (counts ~Binomial: mean 2000, sigma 45 -> 12.5 sigma)

// packed edge payload: src(17b) | ty(2b)<<17 | ldst(7b)<<19  — 26 bits.
// original edge index NOT stored: a_out is rebuilt in original order.

typedef short s16x8 __attribute__((ext_vector_type(8)));
typedef float f32x4 __attribute__((ext_vector_type(4)));

__device__ __forceinline__ short f2bs(float f) {
    __hip_bfloat16 h = __float2bfloat16(f);
    return *reinterpret_cast<short*>(&h);
}

// ---------------------------------------------------------------------------
// Kernel A (MFMA): feat = x @ W, bf16 store, fused el/er.
// W->bf16^T conversion is done per-block in LDS (W is 32KB, L2-resident).
// Block 6250 computes ee[t,h] (12 scalars) AND zeroes cnt[NBUCK] for the
// scatter kernel (stream order guarantees visibility).
// ---------------------------------------------------------------------------
#define XS_STRIDE 136   // 128 + 8 pad shorts
__global__ __launch_bounds__(256) void feat_el_er_kernel(
    const float* __restrict__ x,
    const float* __restrict__ W,
    const float* __restrict__ attn_l,
    const float* __restrict__ attn_r,
    const float* __restrict__ edge_emb,
    const float* __restrict__ W_e,
    const float* __restrict__ attn_e,
    __hip_bfloat16* __restrict__ featb,
    float* __restrict__ el,
    float* __restrict__ eriz,
    float* __restrict__ ee,
    int* __restrict__ cnt)
{
    const int t = threadIdx.x;

    if (blockIdx.x == N_NODES / 16) {
        // ---- service block: zero cnt + compute ee (12 jobs over 4 waves) ----
        for (int j = t; j < NBUCK; j += 256) cnt[j] = 0;
        const int wv = t >> 6, e = t & 63;
        for (int j = wv; j < N_ETYPES * HEADS; j += 4) {
            const int ty = j >> 2, h = j & 3;
            float ef = 0.f;
#pragma unroll
            for (int k = 0; k < EDGE_FEATS; ++k)
                ef += edge_emb[ty * EDGE_FEATS + k] *
                      W_e[k * (HEADS * EDGE_FEATS) + h * EDGE_FEATS + e];
            float v = ef * attn_e[h * EDGE_FEATS + e];
#pragma unroll
            for (int m = 1; m < 64; m <<= 1) v += __shfl_xor(v, m, 64);
            if (e == 0) ee[ty * HEADS + h] = v;
        }
        return;
    }

    __shared__ short Xs[16 * XS_STRIDE];
    __shared__ short Ws[64 * XS_STRIDE];

    const int row0 = blockIdx.x * 16;
    {   // stage x -> bf16 LDS
        const int r = t >> 4, k0 = (t & 15) * 8;
        const float4* xg = (const float4*)(x + (size_t)(row0 + r) * IN_FEATS + k0);
        const float4 v0 = xg[0], v1 = xg[1];
        s16x8 p;
        p[0] = f2bs(v0.x); p[1] = f2bs(v0.y); p[2] = f2bs(v0.z); p[3] = f2bs(v0.w);
        p[4] = f2bs(v1.x); p[5] = f2bs(v1.y); p[6] = f2bs(v1.z); p[7] = f2bs(v1.w);
        *(s16x8*)&Xs[r * XS_STRIDE + k0] = p;
    }
    {   // stage W -> bf16 transposed LDS: Ws[n][k] = W[k][n]
        const int n  = t & 63;
        const int kb = (t >> 6) * 32;
#pragma unroll
        for (int kk = 0; kk < 32; kk += 8) {
            s16x8 p;
#pragma unroll
            for (int j = 0; j < 8; ++j)
                p[j] = f2bs(W[(size_t)(kb + kk + j) * HD + n]);   // coalesced over n
            *(s16x8*)&Ws[n * XS_STRIDE + kb + kk] = p;
        }
    }
    __syncthreads();

    const int w    = t >> 6;
    const int lane = t & 63;
    const int m    = lane & 15;
    const int q    = lane >> 4;

    f32x4 acc = {0.f, 0.f, 0.f, 0.f};
#pragma unroll
    for (int kb = 0; kb < 4; ++kb) {
        const s16x8 af = *(const s16x8*)&Xs[m * XS_STRIDE + kb * 32 + q * 8];
        const s16x8 bf = *(const s16x8*)&Ws[(w * 16 + m) * XS_STRIDE + kb * 32 + q * 8];
        acc = __builtin_amdgcn_mfma_f32_16x16x32_bf16(af, bf, acc, 0, 0, 0);
    }

    const float al = attn_l[w * OUT_FEATS + m];
    const float ar = attn_r[w * OUT_FEATS + m];
#pragma unroll
    for (int r = 0; r < 4; ++r) {
        const int row = row0 + q * 4 + r;
        featb[(size_t)row * HD + w * 16 + m] = __float2bfloat16(acc[r]);
        float cl = acc[r] * al;
        float cr = acc[r] * ar;
#pragma unroll
        for (int msk = 1; msk < 16; msk <<= 1) {
            cl += __shfl_xor(cl, msk, 64);
            cr += __shfl_xor(cr, msk, 64);
        }
        if (m == 0) {
            el[row * HEADS + w] = cl;
            eriz[(size_t)row * 8 + w] = cr;
        }
    }
}

// ---------------------------------------------------------------------------
// Scatter (fuses old hist+scan1+scan2+scatter): per-block LDS histogram,
// ONE global atomicAdd per (block,bucket) claims a contiguous run inside
// bucket j's FIXED region [j*BCAP, j*BCAP+cnt[j]), then LDS-cursor scatter.
// No cross-block scan, no grid sync. cnt[] ends holding bucket counts.
// ---------------------------------------------------------------------------
__global__ __launch_bounds__(256) void scatter_kernel(
    const int* __restrict__ src, const int* __restrict__ dst,
    const int* __restrict__ etype,
    int* __restrict__ cnt, int* __restrict__ sc_bucket)
{
    __shared__ int h[NBUCK];
    const int t = threadIdx.x, b = blockIdx.x;
    for (int j = t; j < NBUCK; j += 256) h[j] = 0;
    __syncthreads();
    const int e0 = b * EPB;
    for (int i = t; i < EPB; i += 256)
        atomicAdd(&h[dst[e0 + i] / NPB], 1);
    __syncthreads();
    for (int j = t; j < NBUCK; j += 256) {
        const int c = h[j];
        h[j] = j * BCAP + (c ? atomicAdd(&cnt[j], c) : 0);  // region cursor
    }
    __syncthreads();
    for (int i = t; i < EPB; i += 256) {
        const int e  = e0 + i;
        const int dn = dst[e];
        const int bu = dn / NPB;
        const int ld = dn - bu * NPB;
        const int slot = atomicAdd(&h[bu], 1);
        sc_bucket[slot] = src[e] | (etype[e] << 17) | (ld << 19);
    }
}

// ---------------------------------------------------------------------------
// CSR finalize: one block per bucket. lo = prefix of cnt[0..b) computed
// REDUNDANTLY per block (<=800 coalesced loads + block reduce) — removes the
// cross-kernel scan dependency. Then LDS-stage, bin over 125 local nodes,
// emit ptr + packed sc_csr {src | ty<<17}.
// ---------------------------------------------------------------------------
__global__ __launch_bounds__(256) void bucket_csr_kernel(
    const int* __restrict__ sc_bucket, const int* __restrict__ cnt,
    int* __restrict__ ptr, int* __restrict__ sc_csr)
{
    __shared__ int sbuf[BCAP];       // 10 KB
    __shared__ int sdeg[128];
    __shared__ int scur[128];
    __shared__ int red[4];
    const int t = threadIdx.x, b = blockIdx.x;

    // redundant prefix: lo = sum cnt[0..b)
    int acc = 0;
    for (int j = t; j < b; j += 256) acc += cnt[j];
#pragma unroll
    for (int m = 1; m < 64; m <<= 1) acc += __shfl_xor(acc, m, 64);
    if ((t & 63) == 0) red[t >> 6] = acc;
    if (t < 128) sdeg[t] = 0;
    __syncthreads();
    const int lo    = red[0] + red[1] + red[2] + red[3];
    const int count = cnt[b];
    const int base  = b * BCAP;
    const bool staged = (count <= BCAP);

    if (staged) {
        for (int i = t; i < count; i += 256) {
            const int v = sc_bucket[base + i];
            sbuf[i] = v;
            atomicAdd(&sdeg[(v >> 19) & 0x7F], 1);
        }
    } else {
        for (int i = t; i < count; i += 256)
            atomicAdd(&sdeg[(sc_bucket[base + i] >> 19) & 0x7F], 1);
    }
    __syncthreads();
    // exclusive scan over 128 (125 used)
    const int orig = (t < 128) ? sdeg[t] : 0;
    for (int off = 1; off < 128; off <<= 1) {
        const int v = (t < 128 && t >= off) ? sdeg[t - off] : 0;
        __syncthreads();
        if (t < 128) sdeg[t] += v;
        __syncthreads();
    }
    if (t < 128) {
        const int excl = sdeg[t] - orig;
        if (t < NPB) ptr[b * NPB + t] = lo + excl;
        scur[t] = lo + excl;             // global packed slot base
    }
    if (b == 0 && t == 0) ptr[N_NODES] = N_EDGES;
    __syncthreads();
    if (staged) {
        for (int i = t; i < count; i += 256) {
            const int v = sbuf[i];
            const int ld = (v >> 19) & 0x7F;
            const int slot = atomicAdd(&scur[ld], 1);
            sc_csr[slot] = v & 0x7FFFF;          // src | ty<<17
        }
    } else {
        for (int i = t; i < count; i += 256) {
            const int v = sc_bucket[base + i];
            const int ld = (v >> 19) & 0x7F;
            const int slot = atomicAdd(&scur[ld], 1);
            sc_csr[slot] = v & 0x7FFFF;
        }
    }
}

// ---------------------------------------------------------------------------
// Kernel C: per-dst aggregation, one wave per node, two in-wave phases.
// Phase 1: 1 lane per (edge,head): exp ONCE per (e,h); w,src -> LDS; z reduce.
// Phase 2: 8 edges x 8 lanes, 16B dwordx4 feat loads, w broadcast from LDS.
// invz written into eriz[n*8+4..7] (shares cacheline with er for attn_out).
// ---------------------------------------------------------------------------
__global__ __launch_bounds__(256) void agg_kernel(
    const int* __restrict__ sc_csr, const int* __restrict__ ptr,
    const float* __restrict__ el, float* __restrict__ eriz,
    const float* __restrict__ ee, const __hip_bfloat16* __restrict__ featb,
    float* __restrict__ rst)
{
    __shared__ float w_lds[4][MAXD_LDS * HEADS];   // 8 KB
    __shared__ int   s_lds[4][MAXD_LDS];           // 2 KB
    const int wid  = threadIdx.x >> 6;
    const int lane = threadIdx.x & 63;
    const int n    = blockIdx.x * 4 + wid;

    const int p0  = ptr[n];
    const int deg = ptr[n + 1] - p0;
    float* wl = w_lds[wid];
    int*   sl = s_lds[wid];
    const ushort* fb = (const ushort*)featb;

    if (deg <= MAXD_LDS) {
        // ---- phase 1: weights, one lane per (edge, head) ----
        const int eo = lane >> 2;          // edge in group of 16
        const int hA = lane & 3;           // head
        const float er_n = eriz[(size_t)n * 8 + hA];
        const float g0 = ee[hA], g1 = ee[HEADS + hA], g2 = ee[2 * HEADS + hA];

        float zacc = 0.f;
        for (int i0 = 0; i0 < deg; i0 += 16) {
            const int idx = i0 + eo;
            if (idx < deg) {
                const int v  = sc_csr[p0 + idx];
                const int sn = v & 0x1FFFF;
                const int ty = v >> 17;
                float s = el[sn * HEADS + hA] + er_n +
                          ((ty == 0) ? g0 : ((ty == 1) ? g1 : g2));
                s = s > 0.f ? s : NEG_SLOPE * s;
                const float w = __expf(s);
                wl[idx * HEADS + hA] = w;
                if (hA == 0) sl[idx] = sn;
                zacc += w;
            }
        }
        // reduce z over edge groups (lane bits 2..5); lane then holds z[lane&3]
        zacc += __shfl_xor(zacc, 4, 64);
        zacc += __shfl_xor(zacc, 8, 64);
        zacc += __shfl_xor(zacc, 16, 64);
        zacc += __shfl_xor(zacc, 32, 64);
        if (lane < 4)
            eriz[(size_t)n * 8 + 4 + lane] = (deg > 0) ? __frcp_rn(zacc) : 0.f;

        // ---- phase 2: accumulate, 8 edges x 8 lanes, 16B loads ----
        const int q8 = lane >> 3;          // edge slot 0..7
        const int c8 = lane & 7;           // col group: cols 8*c8 .. 8*c8+7
        const int h8 = c8 >> 1;            // head of those cols
        const float inv_z = (deg > 0) ? __frcp_rn(__shfl(zacc, h8, 64)) : 0.f;

        float a0 = 0.f, a1 = 0.f, a2 = 0.f, a3 = 0.f;
        float a4 = 0.f, a5 = 0.f, a6 = 0.f, a7 = 0.f;
        int i = 0;
        for (; i + 8 <= deg; i += 8) {
            const int idx = i + q8;
            const int sA = sl[idx];
            const float wA = wl[idx * HEADS + h8];
            const uint4 fA = *(const uint4*)(fb + ((size_t)sA << 6) + (c8 << 3));
            a0 += __uint_as_float(fA.x << 16) * wA;
            a1 += __uint_as_float(fA.x & 0xFFFF0000u) * wA;
            a2 += __uint_as_float(fA.y << 16) * wA;
            a3 += __uint_as_float(fA.y & 0xFFFF0000u) * wA;
            a4 += __uint_as_float(fA.z << 16) * wA;
            a5 += __uint_as_float(fA.z & 0xFFFF0000u) * wA;
            a6 += __uint_as_float(fA.w << 16) * wA;
            a7 += __uint_as_float(fA.w & 0xFFFF0000u) * wA;
        }
        if (i + q8 < deg) {                // tail (<8 edges), one guarded step
            const int idx = i + q8;
            const int sA = sl[idx];
            const float wA = wl[idx * HEADS + h8];
            const uint4 fA = *(const uint4*)(fb + ((size_t)sA << 6) + (c8 << 3));
            a0 += __uint_as_float(fA.x << 16) * wA;
            a1 += __uint_as_float(fA.x & 0xFFFF0000u) * wA;
            a2 += __uint_as_float(fA.y << 16) * wA;
            a3 += __uint_as_float(fA.y & 0xFFFF0000u) * wA;
            a4 += __uint_as_float(fA.z << 16) * wA;
            a5 += __uint_as_float(fA.z & 0xFFFF0000u) * wA;
            a6 += __uint_as_float(fA.w << 16) * wA;
            a7 += __uint_as_float(fA.w & 0xFFFF0000u) * wA;
        }
        // reduce over the 8 edge slots (lane bits 3..5)
        a0 += __shfl_xor(a0, 8, 64); a0 += __shfl_xor(a0, 16, 64); a0 += __shfl_xor(a0, 32, 64);
        a1 += __shfl_xor(a1, 8, 64); a1 += __shfl_xor(a1, 16, 64); a1 += __shfl_xor(a1, 32, 64);
        a2 += __shfl_xor(a2, 8, 64); a2 += __shfl_xor(a2, 16, 64); a2 += __shfl_xor(a2, 32, 64);
        a3 += __shfl_xor(a3, 8, 64); a3 += __shfl_xor(a3, 16, 64); a3 += __shfl_xor(a3, 32, 64);
        a4 += __shfl_xor(a4, 8, 64); a4 += __shfl_xor(a4, 16, 64); a4 += __shfl_xor(a4, 32, 64);
        a5 += __shfl_xor(a5, 8, 64); a5 += __shfl_xor(a5, 16, 64); a5 += __shfl_xor(a5, 32, 64);
        a6 += __shfl_xor(a6, 8, 64); a6 += __shfl_xor(a6, 16, 64); a6 += __shfl_xor(a6, 32, 64);
        a7 += __shfl_xor(a7, 8, 64); a7 += __shfl_xor(a7, 16, 64); a7 += __shfl_xor(a7, 32, 64);
        if (q8 == 0) {
            f32x4 v0 = {a0 * inv_z, a1 * inv_z, a2 * inv_z, a3 * inv_z};
            f32x4 v1 = {a4 * inv_z, a5 * inv_z, a6 * inv_z, a7 * inv_z};
            *(f32x4*)(rst + (size_t)n * HD + (c8 << 3))     = v0;
            *(f32x4*)(rst + (size_t)n * HD + (c8 << 3) + 4) = v1;
        }
    } else {
        // ---- rare big-degree path: two passes, recompute ----
        const int hA = lane & 3;
        const int eo = lane >> 2;
        const float er_nA = eriz[(size_t)n * 8 + hA];
        const float a0 = ee[hA], a1 = ee[HEADS + hA], a2 = ee[2 * HEADS + hA];
        float zacc = 0.f;
        for (int base = 0; base < deg; base += 16) {
            const int idx = base + eo;
            if (idx < deg) {
                const int v  = sc_csr[p0 + idx];
                const int sn = v & 0x1FFFF;
                const int ty = v >> 17;
                float s = el[sn * HEADS + hA] + er_nA + ((ty == 0) ? a0 : ((ty == 1) ? a1 : a2));
                s = s > 0.f ? s : NEG_SLOPE * s;
                zacc += __expf(s);
            }
        }
#pragma unroll
        for (int m = 4; m < 64; m <<= 1) zacc += __shfl_xor(zacc, m, 64);
        if (lane < 4) eriz[(size_t)n * 8 + 4 + lane] = __frcp_rn(zacc);
        const int h = lane >> 4;
        const float inv_z = __frcp_rn(__shfl(zacc, h, 64));
        const float er_n = eriz[(size_t)n * 8 + h];
        const float g0 = ee[h], g1 = ee[HEADS + h], g2 = ee[2 * HEADS + h];
        float racc = 0.f;
        for (int i = 0; i < deg; ++i) {
            const int v  = sc_csr[p0 + i];
            const int sn = v & 0x1FFFF;
            const int ty = v >> 17;
            float s = el[sn * HEADS + h] + er_n + ((ty == 0) ? g0 : ((ty == 1) ? g1 : g2));
            s = s > 0.f ? s : NEG_SLOPE * s;
            const float a = __expf(s) * inv_z;
            racc += __bfloat162float(featb[(size_t)sn * HD + lane]) * a;
        }
        rst[(size_t)n * HD + lane] = racc;
    }
}

// ---------------------------------------------------------------------------
// Kernel D: a_out in ORIGINAL edge order — fully coalesced float4 writes.
// er+invz share one 32B cacheline per node (eriz).
// ---------------------------------------------------------------------------
__global__ __launch_bounds__(256) void attn_out_kernel(
    const int* __restrict__ src, const int* __restrict__ dst,
    const int* __restrict__ etype,
    const float* __restrict__ el, const float* __restrict__ eriz,
    const float* __restrict__ ee,
    float* __restrict__ a_out)
{
    const int e = blockIdx.x * 256 + threadIdx.x;   // grid exact: E/256
    const int sN = src[e];
    const int dN = dst[e];
    const int ty = etype[e];
    const float4 l4 = *(const float4*)(el + (size_t)sN * HEADS);
    const float4 r4 = *(const float4*)(eriz + (size_t)dN * 8);
    const float4 iz = *(const float4*)(eriz + (size_t)dN * 8 + 4);
    const float4 g4 = *(const float4*)(ee + (size_t)ty * HEADS);
    float4 a;
    float s;
    s = l4.x + r4.x + g4.x; s = s > 0.f ? s : NEG_SLOPE * s; a.x = __expf(s) * iz.x;
    s = l4.y + r4.y + g4.y; s = s > 0.f ? s : NEG_SLOPE * s; a.y = __expf(s) * iz.y;
    s = l4.z + r4.z + g4.z; s = s > 0.f ? s : NEG_SLOPE * s; a.z = __expf(s) * iz.z;
    s = l4.w + r4.w + g4.w; s = s > 0.f ? s : NEG_SLOPE * s; a.w = __expf(s) * iz.w;
    *(float4*)(a_out + (size_t)e * HEADS) = a;
}

extern "C" void kernel_launch(void* const* d_in, const int* in_sizes, int n_in,
                              void* d_out, int out_size, void* d_ws, size_t ws_size,
                              hipStream_t stream)
{
    const float* x        = (const float*)d_in[0];
    const float* W        = (const float*)d_in[1];
    const float* W_e      = (const float*)d_in[2];
    const float* attn_l   = (const float*)d_in[3];
    const float* attn_r   = (const float*)d_in[4];
    const float* attn_e   = (const float*)d_in[5];
    const float* edge_emb = (const float*)d_in[6];
    const int* src   = (const int*)d_in[7];
    const int* dst   = (const int*)d_in[8];
    const int* etype = (const int*)d_in[9];

    float* out     = (float*)d_out;
    float* rst_out = out;                              // N*H*D
    float* a_out   = out + (size_t)N_NODES * HD;       // E*H

    char* w = (char*)d_ws;
    __hip_bfloat16* featb = (__hip_bfloat16*)w; w += (size_t)N_NODES * HD * 2;   // 12.8 MB
    float* el    = (float*)w;  w += (size_t)N_NODES * HEADS * 4;    //  1.6 MB
    float* eriz  = (float*)w;  w += (size_t)N_NODES * 8 * 4;        //  3.2 MB (er|invz)
    float* ee    = (float*)w;  w += 64;
    int*   ptr   = (int*)w;    w += (size_t)(N_NODES + 4) * 4;      //  0.4 MB
    int*   cnt   = (int*)w;    w += (size_t)(NBUCK + 8) * 4;        //  3.2 KB
    int*   sc_bucket = (int*)w; w += (size_t)NBUCK * BCAP * 4;      //  8.2 MB (fixed regions)
    int*   sc_csr    = (int*)w; w += (size_t)N_EDGES * 4;           //  6.4 MB (packed)
    // total ~32.6 MB

    // 1) GEMM + el/er + ee + zero(cnt)
    feat_el_er_kernel<<<N_NODES / 16 + 1, 256, 0, stream>>>(
        x, W, attn_l, attn_r, edge_emb, W_e, attn_e, featb, el, eriz, ee, cnt);

    // 2) scatter into fixed-capacity bucket regions (replaces hist+scan1+scan2+scatter)
    scatter_kernel<<<PBLK, 256, 0, stream>>>(src, dst, etype, cnt, sc_bucket);

    // 3) CSR finalize (redundant per-block prefix of cnt — no scan kernel)
    bucket_csr_kernel<<<NBUCK, 256, 0, stream>>>(sc_bucket, cnt, ptr, sc_csr);

    // 4) aggregation
    agg_kernel<<<N_NODES / 4, 256, 0, stream>>>(
        sc_csr, ptr, el, eriz, ee, featb, rst_out);

    // 5) attention weights in original edge order
    attn_out_kernel<<<N_EDGES / 256, 256, 0, stream>>>(
        src, dst, etype, el, eriz, ee, a_out);
}

// Round 6
// 278.688 us; speedup vs baseline: 2.4309x; 1.0022x over previous
//
#include <hip/hip_runtime.h>
#include <hip/hip_bf16.h>

#define N_NODES   100000
#define N_EDGES   1600000
#define N_ETYPES  3
#define IN_FEATS  128
#define HEADS     4
#define OUT_FEATS 16
#define EDGE_FEATS 64
#define HD        64            // HEADS*OUT_FEATS
#define NEG_SLOPE 0.2f
#define MAXD_LDS  128           // agg fast-path max degree (Poisson(16): P(>128)~0)

#define NBUCK     800           // buckets for counting sort
#define NPB       125           // nodes per bucket (800*125 = N_NODES)
#define PBLK      400           // blocks in scatter pass
#define EPB       4000          // edges per block (400*4000 = N_EDGES)
#define BCAP      2560          // fixed bucket-region capacity AND LDS stage cap
                                // (counts ~Binomial: mean 2000, sigma 45 -> 12.5 sigma)
#define FROWS     32            // rows per feat block (100000/32 = 3125 exact)

// packed edge payload: src(17b) | ty(2b)<<17 | ldst(7b)<<19  — 26 bits.
// original edge index NOT stored: a_out is rebuilt in original order.

typedef short s16x8 __attribute__((ext_vector_type(8)));
typedef float f32x4 __attribute__((ext_vector_type(4)));

__device__ __forceinline__ short f2bs(float f) {
    __hip_bfloat16 h = __float2bfloat16(f);
    return *reinterpret_cast<short*>(&h);
}

// ---------------------------------------------------------------------------
// Prep: WT bf16 [64][128]  (WT[n][k] = W[k][n]) — separate 2us kernel;
// cheaper than redundant per-GEMM-block conversion (launch gap ~2us, R5).
// ---------------------------------------------------------------------------
__global__ __launch_bounds__(256) void wt_prep_kernel(
    const float* __restrict__ W, short* __restrict__ WTb)
{
    const int t = blockIdx.x * 256 + threadIdx.x;   // 0..8191
    const int k = t >> 6, n = t & 63;
    WTb[n * IN_FEATS + k] = f2bs(W[t]);
}

// ---------------------------------------------------------------------------
// Kernel A (MFMA): feat = x @ W, bf16 store, fused el/er.
// 32 rows/block; B-fragments read DIRECT from WTb (16KB, L1-resident) — no
// Ws LDS stage. Service block (3125) zeroes cnt + computes ee.
// ---------------------------------------------------------------------------
#define XS_STRIDE 136   // 128 + 8 pad shorts
__global__ __launch_bounds__(256) void feat_el_er_kernel(
    const float* __restrict__ x,
    const short* __restrict__ WTb,
    const float* __restrict__ attn_l,
    const float* __restrict__ attn_r,
    const float* __restrict__ edge_emb,
    const float* __restrict__ W_e,
    const float* __restrict__ attn_e,
    __hip_bfloat16* __restrict__ featb,
    float* __restrict__ el,
    float* __restrict__ eriz,
    float* __restrict__ ee,
    int* __restrict__ cnt)
{
    const int t = threadIdx.x;

    if (blockIdx.x == N_NODES / FROWS) {
        // ---- service block: zero cnt + compute ee (12 jobs over 4 waves) ----
        for (int j = t; j < NBUCK; j += 256) cnt[j] = 0;
        const int wv = t >> 6, e = t & 63;
        for (int j = wv; j < N_ETYPES * HEADS; j += 4) {
            const int ty = j >> 2, h = j & 3;
            float ef = 0.f;
#pragma unroll
            for (int k = 0; k < EDGE_FEATS; ++k)
                ef += edge_emb[ty * EDGE_FEATS + k] *
                      W_e[k * (HEADS * EDGE_FEATS) + h * EDGE_FEATS + e];
            float v = ef * attn_e[h * EDGE_FEATS + e];
#pragma unroll
            for (int m = 1; m < 64; m <<= 1) v += __shfl_xor(v, m, 64);
            if (e == 0) ee[ty * HEADS + h] = v;
        }
        return;
    }

    __shared__ short Xs[FROWS * XS_STRIDE];   // 8.7 KB

    const int row0 = blockIdx.x * FROWS;
    {   // stage x -> bf16 LDS: 16 elems/thread
        const int r = t >> 3, k0 = (t & 7) * 16;
        const float4* xg = (const float4*)(x + (size_t)(row0 + r) * IN_FEATS + k0);
        const float4 v0 = xg[0], v1 = xg[1], v2 = xg[2], v3 = xg[3];
        s16x8 p0, p1;
        p0[0] = f2bs(v0.x); p0[1] = f2bs(v0.y); p0[2] = f2bs(v0.z); p0[3] = f2bs(v0.w);
        p0[4] = f2bs(v1.x); p0[5] = f2bs(v1.y); p0[6] = f2bs(v1.z); p0[7] = f2bs(v1.w);
        p1[0] = f2bs(v2.x); p1[1] = f2bs(v2.y); p1[2] = f2bs(v2.z); p1[3] = f2bs(v2.w);
        p1[4] = f2bs(v3.x); p1[5] = f2bs(v3.y); p1[6] = f2bs(v3.z); p1[7] = f2bs(v3.w);
        *(s16x8*)&Xs[r * XS_STRIDE + k0]     = p0;
        *(s16x8*)&Xs[r * XS_STRIDE + k0 + 8] = p1;
    }

    const int w    = t >> 6;
    const int lane = t & 63;
    const int m    = lane & 15;
    const int q    = lane >> 4;

    // B fragments straight from global (L1-hot 16KB), hoisted across row-groups
    s16x8 bfr[4];
#pragma unroll
    for (int kb = 0; kb < 4; ++kb)
        bfr[kb] = *(const s16x8*)(WTb + (size_t)(w * 16 + m) * IN_FEATS + kb * 32 + q * 8);

    const float al = attn_l[w * OUT_FEATS + m];
    const float ar = attn_r[w * OUT_FEATS + m];

    __syncthreads();

#pragma unroll
    for (int rg = 0; rg < 2; ++rg) {
        f32x4 acc = {0.f, 0.f, 0.f, 0.f};
#pragma unroll
        for (int kb = 0; kb < 4; ++kb) {
            const s16x8 af = *(const s16x8*)&Xs[(rg * 16 + m) * XS_STRIDE + kb * 32 + q * 8];
            acc = __builtin_amdgcn_mfma_f32_16x16x32_bf16(af, bfr[kb], acc, 0, 0, 0);
        }
#pragma unroll
        for (int r = 0; r < 4; ++r) {
            const int row = row0 + rg * 16 + q * 4 + r;
            featb[(size_t)row * HD + w * 16 + m] = __float2bfloat16(acc[r]);
            float cl = acc[r] * al;
            float cr = acc[r] * ar;
#pragma unroll
            for (int msk = 1; msk < 16; msk <<= 1) {
                cl += __shfl_xor(cl, msk, 64);
                cr += __shfl_xor(cr, msk, 64);
            }
            if (m == 0) {
                el[row * HEADS + w] = cl;
                eriz[(size_t)row * 8 + w] = cr;
            }
        }
    }
}

// ---------------------------------------------------------------------------
// Scatter (fuses hist+scan+scatter): per-block LDS histogram, ONE global
// atomicAdd per (block,bucket) claims a contiguous run inside bucket j's
// FIXED region [j*BCAP, ...), LDS-cursor scatter. bu/ld cached in registers
// between passes (no 2nd dst read, no 2nd division).
// ---------------------------------------------------------------------------
__global__ __launch_bounds__(256) void scatter_kernel(
    const int* __restrict__ src, const int* __restrict__ dst,
    const int* __restrict__ etype,
    int* __restrict__ cnt, int* __restrict__ sc_bucket)
{
    __shared__ int h[NBUCK];
    int buld[16];                      // EPB/256 = 15.625 -> <=16 iters
    const int t = threadIdx.x, b = blockIdx.x;
    for (int j = t; j < NBUCK; j += 256) h[j] = 0;
    __syncthreads();
    const int e0 = b * EPB;
    int k = 0;
    for (int i = t; i < EPB; i += 256, ++k) {
        const int dn = dst[e0 + i];
        const int bu = dn / NPB;
        const int ld = dn - bu * NPB;
        buld[k] = bu | (ld << 16);
        atomicAdd(&h[bu], 1);
    }
    __syncthreads();
    for (int j = t; j < NBUCK; j += 256) {
        const int c = h[j];
        h[j] = j * BCAP + (c ? atomicAdd(&cnt[j], c) : 0);  // region cursor
    }
    __syncthreads();
    k = 0;
    for (int i = t; i < EPB; i += 256, ++k) {
        const int e  = e0 + i;
        const int bu = buld[k] & 0xFFFF;
        const int ld = buld[k] >> 16;
        const int slot = atomicAdd(&h[bu], 1);
        sc_bucket[slot] = src[e] | (etype[e] << 17) | (ld << 19);
    }
}

// ---------------------------------------------------------------------------
// CSR finalize: one block per bucket. lo = prefix of cnt[0..b) computed
// redundantly per block. Hist uses 4 per-wave LDS histograms (4x less
// atomic contention on 125 hot counters). Emit ptr + packed sc_csr.
// ---------------------------------------------------------------------------
__global__ __launch_bounds__(256) void bucket_csr_kernel(
    const int* __restrict__ sc_bucket, const int* __restrict__ cnt,
    int* __restrict__ ptr, int* __restrict__ sc_csr)
{
    __shared__ int sbuf[BCAP];        // 10 KB
    __shared__ int sdeg4[4][128];     // per-wave hists, 2 KB
    __shared__ int sdg[128];
    __shared__ int scur[128];
    __shared__ int red[4];
    const int t = threadIdx.x, b = blockIdx.x;
    const int wid = t >> 6;

    // redundant prefix: lo = sum cnt[0..b)
    int acc = 0;
    for (int j = t; j < b; j += 256) acc += cnt[j];
#pragma unroll
    for (int m = 1; m < 64; m <<= 1) acc += __shfl_xor(acc, m, 64);
    if ((t & 63) == 0) red[wid] = acc;
    sdeg4[0][t & 127] = 0; sdeg4[1][t & 127] = 0;
    if (t < 128) { sdeg4[2][t] = 0; sdeg4[3][t] = 0; }   // all 512 zeroed (256 thr x2)
    __syncthreads();
    const int lo    = red[0] + red[1] + red[2] + red[3];
    const int count = cnt[b];
    const int base  = b * BCAP;
    const bool staged = (count <= BCAP);

    if (staged) {
        for (int i = t; i < count; i += 256) {
            const int v = sc_bucket[base + i];
            sbuf[i] = v;
            atomicAdd(&sdeg4[wid][(v >> 19) & 0x7F], 1);
        }
    } else {
        for (int i = t; i < count; i += 256)
            atomicAdd(&sdeg4[wid][(sc_bucket[base + i] >> 19) & 0x7F], 1);
    }
    __syncthreads();
    // combine + exclusive scan over 128 (125 used)
    int orig = 0;
    if (t < 128) {
        orig = sdeg4[0][t] + sdeg4[1][t] + sdeg4[2][t] + sdeg4[3][t];
        sdg[t] = orig;
    }
    __syncthreads();
    for (int off = 1; off < 128; off <<= 1) {
        const int v = (t < 128 && t >= off) ? sdg[t - off] : 0;
        __syncthreads();
        if (t < 128) sdg[t] += v;
        __syncthreads();
    }
    if (t < 128) {
        const int excl = sdg[t] - orig;
        if (t < NPB) ptr[b * NPB + t] = lo + excl;
        scur[t] = lo + excl;             // global packed slot base
    }
    if (b == 0 && t == 0) ptr[N_NODES] = N_EDGES;
    __syncthreads();
    if (staged) {
        for (int i = t; i < count; i += 256) {
            const int v = sbuf[i];
            const int ld = (v >> 19) & 0x7F;
            const int slot = atomicAdd(&scur[ld], 1);
            sc_csr[slot] = v & 0x7FFFF;          // src | ty<<17
        }
    } else {
        for (int i = t; i < count; i += 256) {
            const int v = sc_bucket[base + i];
            const int ld = (v >> 19) & 0x7F;
            const int slot = atomicAdd(&scur[ld], 1);
            sc_csr[slot] = v & 0x7FFFF;
        }
    }
}

// ---------------------------------------------------------------------------
// Kernel C: per-dst aggregation, one wave per node, two in-wave phases.
// Phase 1: 1 lane per (edge,head): exp ONCE per (e,h); w,src -> LDS; z reduce.
// Phase 2: 8 edges x 8 lanes, 16B dwordx4 feat loads, w broadcast from LDS.
// invz written into eriz[n*8+4..7] (shares cacheline with er for attn_out).
// ---------------------------------------------------------------------------
__global__ __launch_bounds__(256) void agg_kernel(
    const int* __restrict__ sc_csr, const int* __restrict__ ptr,
    const float* __restrict__ el, float* __restrict__ eriz,
    const float* __restrict__ ee, const __hip_bfloat16* __restrict__ featb,
    float* __restrict__ rst)
{
    __shared__ float w_lds[4][MAXD_LDS * HEADS];   // 8 KB
    __shared__ int   s_lds[4][MAXD_LDS];           // 2 KB
    const int wid  = threadIdx.x >> 6;
    const int lane = threadIdx.x & 63;
    const int n    = blockIdx.x * 4 + wid;

    const int p0  = ptr[n];
    const int deg = ptr[n + 1] - p0;
    float* wl = w_lds[wid];
    int*   sl = s_lds[wid];
    const ushort* fb = (const ushort*)featb;

    if (deg <= MAXD_LDS) {
        // ---- phase 1: weights, one lane per (edge, head) ----
        const int eo = lane >> 2;          // edge in group of 16
        const int hA = lane & 3;           // head
        const float er_n = eriz[(size_t)n * 8 + hA];
        const float g0 = ee[hA], g1 = ee[HEADS + hA], g2 = ee[2 * HEADS + hA];

        float zacc = 0.f;
        for (int i0 = 0; i0 < deg; i0 += 16) {
            const int idx = i0 + eo;
            if (idx < deg) {
                const int v  = sc_csr[p0 + idx];
                const int sn = v & 0x1FFFF;
                const int ty = v >> 17;
                float s = el[sn * HEADS + hA] + er_n +
                          ((ty == 0) ? g0 : ((ty == 1) ? g1 : g2));
                s = s > 0.f ? s : NEG_SLOPE * s;
                const float w = __expf(s);
                wl[idx * HEADS + hA] = w;
                if (hA == 0) sl[idx] = sn;
                zacc += w;
            }
        }
        // reduce z over edge groups (lane bits 2..5); lane then holds z[lane&3]
        zacc += __shfl_xor(zacc, 4, 64);
        zacc += __shfl_xor(zacc, 8, 64);
        zacc += __shfl_xor(zacc, 16, 64);
        zacc += __shfl_xor(zacc, 32, 64);
        if (lane < 4)
            eriz[(size_t)n * 8 + 4 + lane] = (deg > 0) ? __frcp_rn(zacc) : 0.f;

        // ---- phase 2: accumulate, 8 edges x 8 lanes, 16B loads ----
        const int q8 = lane >> 3;          // edge slot 0..7
        const int c8 = lane & 7;           // col group: cols 8*c8 .. 8*c8+7
        const int h8 = c8 >> 1;            // head of those cols
        const float inv_z = (deg > 0) ? __frcp_rn(__shfl(zacc, h8, 64)) : 0.f;

        float a0 = 0.f, a1 = 0.f, a2 = 0.f, a3 = 0.f;
        float a4 = 0.f, a5 = 0.f, a6 = 0.f, a7 = 0.f;
        int i = 0;
        for (; i + 8 <= deg; i += 8) {
            const int idx = i + q8;
            const int sA = sl[idx];
            const float wA = wl[idx * HEADS + h8];
            const uint4 fA = *(const uint4*)(fb + ((size_t)sA << 6) + (c8 << 3));
            a0 += __uint_as_float(fA.x << 16) * wA;
            a1 += __uint_as_float(fA.x & 0xFFFF0000u) * wA;
            a2 += __uint_as_float(fA.y << 16) * wA;
            a3 += __uint_as_float(fA.y & 0xFFFF0000u) * wA;
            a4 += __uint_as_float(fA.z << 16) * wA;
            a5 += __uint_as_float(fA.z & 0xFFFF0000u) * wA;
            a6 += __uint_as_float(fA.w << 16) * wA;
            a7 += __uint_as_float(fA.w & 0xFFFF0000u) * wA;
        }
        if (i + q8 < deg) {                // tail (<8 edges), one guarded step
            const int idx = i + q8;
            const int sA = sl[idx];
            const float wA = wl[idx * HEADS + h8];
            const uint4 fA = *(const uint4*)(fb + ((size_t)sA << 6) + (c8 << 3));
            a0 += __uint_as_float(fA.x << 16) * wA;
            a1 += __uint_as_float(fA.x & 0xFFFF0000u) * wA;
            a2 += __uint_as_float(fA.y << 16) * wA;
            a3 += __uint_as_float(fA.y & 0xFFFF0000u) * wA;
            a4 += __uint_as_float(fA.z << 16) * wA;
            a5 += __uint_as_float(fA.z & 0xFFFF0000u) * wA;
            a6 += __uint_as_float(fA.w << 16) * wA;
            a7 += __uint_as_float(fA.w & 0xFFFF0000u) * wA;
        }
        // reduce over the 8 edge slots (lane bits 3..5)
        a0 += __shfl_xor(a0, 8, 64); a0 += __shfl_xor(a0, 16, 64); a0 += __shfl_xor(a0, 32, 64);
        a1 += __shfl_xor(a1, 8, 64); a1 += __shfl_xor(a1, 16, 64); a1 += __shfl_xor(a1, 32, 64);
        a2 += __shfl_xor(a2, 8, 64); a2 += __shfl_xor(a2, 16, 64); a2 += __shfl_xor(a2, 32, 64);
        a3 += __shfl_xor(a3, 8, 64); a3 += __shfl_xor(a3, 16, 64); a3 += __shfl_xor(a3, 32, 64);
        a4 += __shfl_xor(a4, 8, 64); a4 += __shfl_xor(a4, 16, 64); a4 += __shfl_xor(a4, 32, 64);
        a5 += __shfl_xor(a5, 8, 64); a5 += __shfl_xor(a5, 16, 64); a5 += __shfl_xor(a5, 32, 64);
        a6 += __shfl_xor(a6, 8, 64); a6 += __shfl_xor(a6, 16, 64); a6 += __shfl_xor(a6, 32, 64);
        a7 += __shfl_xor(a7, 8, 64); a7 += __shfl_xor(a7, 16, 64); a7 += __shfl_xor(a7, 32, 64);
        if (q8 == 0) {
            f32x4 v0 = {a0 * inv_z, a1 * inv_z, a2 * inv_z, a3 * inv_z};
            f32x4 v1 = {a4 * inv_z, a5 * inv_z, a6 * inv_z, a7 * inv_z};
            *(f32x4*)(rst + (size_t)n * HD + (c8 << 3))     = v0;
            *(f32x4*)(rst + (size_t)n * HD + (c8 << 3) + 4) = v1;
        }
    } else {
        // ---- rare big-degree path: two passes, recompute ----
        const int hA = lane & 3;
        const int eo = lane >> 2;
        const float er_nA = eriz[(size_t)n * 8 + hA];
        const float a0 = ee[hA], a1 = ee[HEADS + hA], a2 = ee[2 * HEADS + hA];
        float zacc = 0.f;
        for (int base = 0; base < deg; base += 16) {
            const int idx = base + eo;
            if (idx < deg) {
                const int v  = sc_csr[p0 + idx];
                const int sn = v & 0x1FFFF;
                const int ty = v >> 17;
                float s = el[sn * HEADS + hA] + er_nA + ((ty == 0) ? a0 : ((ty == 1) ? a1 : a2));
                s = s > 0.f ? s : NEG_SLOPE * s;
                zacc += __expf(s);
            }
        }
#pragma unroll
        for (int m = 4; m < 64; m <<= 1) zacc += __shfl_xor(zacc, m, 64);
        if (lane < 4) eriz[(size_t)n * 8 + 4 + lane] = __frcp_rn(zacc);
        const int h = lane >> 4;
        const float inv_z = __frcp_rn(__shfl(zacc, h, 64));
        const float er_n = eriz[(size_t)n * 8 + h];
        const float g0 = ee[h], g1 = ee[HEADS + h], g2 = ee[2 * HEADS + h];
        float racc = 0.f;
        for (int i = 0; i < deg; ++i) {
            const int v  = sc_csr[p0 + i];
            const int sn = v & 0x1FFFF;
            const int ty = v >> 17;
            float s = el[sn * HEADS + h] + er_n + ((ty == 0) ? g0 : ((ty == 1) ? g1 : g2));
            s = s > 0.f ? s : NEG_SLOPE * s;
            const float a = __expf(s) * inv_z;
            racc += __bfloat162float(featb[(size_t)sn * HD + lane]) * a;
        }
        rst[(size_t)n * HD + lane] = racc;
    }
}

// ---------------------------------------------------------------------------
// Kernel D: a_out in ORIGINAL edge order — fully coalesced float4 writes.
// er+invz share one 32B cacheline per node (eriz).
// ---------------------------------------------------------------------------
__global__ __launch_bounds__(256) void attn_out_kernel(
    const int* __restrict__ src, const int* __restrict__ dst,
    const int* __restrict__ etype,
    const float* __restrict__ el, const float* __restrict__ eriz,
    const float* __restrict__ ee,
    float* __restrict__ a_out)
{
    const int e = blockIdx.x * 256 + threadIdx.x;   // grid exact: E/256
    const int sN = src[e];
    const int dN = dst[e];
    const int ty = etype[e];
    const float4 l4 = *(const float4*)(el + (size_t)sN * HEADS);
    const float4 r4 = *(const float4*)(eriz + (size_t)dN * 8);
    const float4 iz = *(const float4*)(eriz + (size_t)dN * 8 + 4);
    const float4 g4 = *(const float4*)(ee + (size_t)ty * HEADS);
    float4 a;
    float s;
    s = l4.x + r4.x + g4.x; s = s > 0.f ? s : NEG_SLOPE * s; a.x = __expf(s) * iz.x;
    s = l4.y + r4.y + g4.y; s = s > 0.f ? s : NEG_SLOPE * s; a.y = __expf(s) * iz.y;
    s = l4.z + r4.z + g4.z; s = s > 0.f ? s : NEG_SLOPE * s; a.z = __expf(s) * iz.z;
    s = l4.w + r4.w + g4.w; s = s > 0.f ? s : NEG_SLOPE * s; a.w = __expf(s) * iz.w;
    *(float4*)(a_out + (size_t)e * HEADS) = a;
}

extern "C" void kernel_launch(void* const* d_in, const int* in_sizes, int n_in,
                              void* d_out, int out_size, void* d_ws, size_t ws_size,
                              hipStream_t stream)
{
    const float* x        = (const float*)d_in[0];
    const float* W        = (const float*)d_in[1];
    const float* W_e      = (const float*)d_in[2];
    const float* attn_l   = (const float*)d_in[3];
    const float* attn_r   = (const float*)d_in[4];
    const float* attn_e   = (const float*)d_in[5];
    const float* edge_emb = (const float*)d_in[6];
    const int* src   = (const int*)d_in[7];
    const int* dst   = (const int*)d_in[8];
    const int* etype = (const int*)d_in[9];

    float* out     = (float*)d_out;
    float* rst_out = out;                              // N*H*D
    float* a_out   = out + (size_t)N_NODES * HD;       // E*H

    char* w = (char*)d_ws;
    __hip_bfloat16* featb = (__hip_bfloat16*)w; w += (size_t)N_NODES * HD * 2;   // 12.8 MB
    float* el    = (float*)w;  w += (size_t)N_NODES * HEADS * 4;    //  1.6 MB
    float* eriz  = (float*)w;  w += (size_t)N_NODES * 8 * 4;        //  3.2 MB (er|invz)
    float* ee    = (float*)w;  w += 64;
    int*   ptr   = (int*)w;    w += (size_t)(N_NODES + 4) * 4;      //  0.4 MB
    int*   cnt   = (int*)w;    w += (size_t)(NBUCK + 8) * 4;        //  3.2 KB
    short* WTb   = (short*)w;  w += (size_t)HD * IN_FEATS * 2;      //   16 KB
    int*   sc_bucket = (int*)w; w += (size_t)NBUCK * BCAP * 4;      //  8.2 MB (fixed regions)
    int*   sc_csr    = (int*)w; w += (size_t)N_EDGES * 4;           //  6.4 MB (packed)
    // total ~32.6 MB

    // 1) W -> bf16^T (once; ~2us incl. launch — cheaper than per-block conv)
    wt_prep_kernel<<<(IN_FEATS * HD) / 256, 256, 0, stream>>>(W, WTb);

    // 2) GEMM + el/er + ee + zero(cnt); 32 rows/block, B direct from L1
    feat_el_er_kernel<<<N_NODES / FROWS + 1, 256, 0, stream>>>(
        x, WTb, attn_l, attn_r, edge_emb, W_e, attn_e, featb, el, eriz, ee, cnt);

    // 3) scatter into fixed-capacity bucket regions
    scatter_kernel<<<PBLK, 256, 0, stream>>>(src, dst, etype, cnt, sc_bucket);

    // 4) CSR finalize
    bucket_csr_kernel<<<NBUCK, 256, 0, stream>>>(sc_bucket, cnt, ptr, sc_csr);

    // 5) aggregation
    agg_kernel<<<N_NODES / 4, 256, 0, stream>>>(
        sc_csr, ptr, el, eriz, ee, featb, rst_out);

    // 6) attention weights in original edge order
    attn_out_kernel<<<N_EDGES / 256, 256, 0, stream>>>(
        src, dst, etype, el, eriz, ee, a_out);
}

// Round 7
// 276.250 us; speedup vs baseline: 2.4524x; 1.0088x over previous
//
#include <hip/hip_runtime.h>
#include <hip/hip_bf16.h>

#define N_NODES   100000
#define N_EDGES   1600000
#define N_ETYPES  3
#define IN_FEATS  128
#define HEADS     4
#define OUT_FEATS 16
#define EDGE_FEATS 64
#define HD        64            // HEADS*OUT_FEATS
#define NEG_SLOPE 0.2f
#define MAXD_LDS  128           // agg fast-path max degree (Poisson(16): P(>128)~0)

#define NBUCK     800           // buckets for counting sort
#define NPB       125           // nodes per bucket (800*125 = N_NODES)
#define PBLK      400           // blocks in scatter pass
#define EPB       4000          // edges per block (400*4000 = N_EDGES)
#define BCAP      2560          // fixed bucket-region capacity AND LDS stage cap
#define FROWS     32            // rows per feat block (100000/32 = 3125 exact)

// packed edge payload: src(17b) | ty(2b)<<17 | ldst(7b)<<19  — 26 bits.

typedef short s16x8 __attribute__((ext_vector_type(8)));
typedef float f32x4 __attribute__((ext_vector_type(4)));

__device__ __forceinline__ short f2bs(float f) {
    __hip_bfloat16 h = __float2bfloat16(f);
    return *reinterpret_cast<short*>(&h);
}

// ---------------------------------------------------------------------------
// Prep: WT bf16 [64][128]  (WT[n][k] = W[k][n])
// ---------------------------------------------------------------------------
__global__ __launch_bounds__(256) void wt_prep_kernel(
    const float* __restrict__ W, short* __restrict__ WTb)
{
    const int t = blockIdx.x * 256 + threadIdx.x;   // 0..8191
    const int k = t >> 6, n = t & 63;
    WTb[n * IN_FEATS + k] = f2bs(W[t]);
}

// ---------------------------------------------------------------------------
// Kernel A (MFMA): feat = x @ W, bf16 store, fused el/er.
// 32 rows/block; B-fragments direct from WTb (L1-resident). Service block
// zeroes cnt + computes ee.
// ---------------------------------------------------------------------------
#define XS_STRIDE 136   // 128 + 8 pad shorts
__global__ __launch_bounds__(256) void feat_el_er_kernel(
    const float* __restrict__ x,
    const short* __restrict__ WTb,
    const float* __restrict__ attn_l,
    const float* __restrict__ attn_r,
    const float* __restrict__ edge_emb,
    const float* __restrict__ W_e,
    const float* __restrict__ attn_e,
    __hip_bfloat16* __restrict__ featb,
    float* __restrict__ el,
    float* __restrict__ eriz,
    float* __restrict__ ee,
    int* __restrict__ cnt)
{
    const int t = threadIdx.x;

    if (blockIdx.x == N_NODES / FROWS) {
        // ---- service block: zero cnt + compute ee (12 jobs over 4 waves) ----
        for (int j = t; j < NBUCK; j += 256) cnt[j] = 0;
        const int wv = t >> 6, e = t & 63;
        for (int j = wv; j < N_ETYPES * HEADS; j += 4) {
            const int ty = j >> 2, h = j & 3;
            float ef = 0.f;
#pragma unroll
            for (int k = 0; k < EDGE_FEATS; ++k)
                ef += edge_emb[ty * EDGE_FEATS + k] *
                      W_e[k * (HEADS * EDGE_FEATS) + h * EDGE_FEATS + e];
            float v = ef * attn_e[h * EDGE_FEATS + e];
#pragma unroll
            for (int m = 1; m < 64; m <<= 1) v += __shfl_xor(v, m, 64);
            if (e == 0) ee[ty * HEADS + h] = v;
        }
        return;
    }

    __shared__ short Xs[FROWS * XS_STRIDE];   // 8.7 KB

    const int row0 = blockIdx.x * FROWS;
    {   // stage x -> bf16 LDS: 16 elems/thread
        const int r = t >> 3, k0 = (t & 7) * 16;
        const float4* xg = (const float4*)(x + (size_t)(row0 + r) * IN_FEATS + k0);
        const float4 v0 = xg[0], v1 = xg[1], v2 = xg[2], v3 = xg[3];
        s16x8 p0, p1;
        p0[0] = f2bs(v0.x); p0[1] = f2bs(v0.y); p0[2] = f2bs(v0.z); p0[3] = f2bs(v0.w);
        p0[4] = f2bs(v1.x); p0[5] = f2bs(v1.y); p0[6] = f2bs(v1.z); p0[7] = f2bs(v1.w);
        p1[0] = f2bs(v2.x); p1[1] = f2bs(v2.y); p1[2] = f2bs(v2.z); p1[3] = f2bs(v2.w);
        p1[4] = f2bs(v3.x); p1[5] = f2bs(v3.y); p1[6] = f2bs(v3.z); p1[7] = f2bs(v3.w);
        *(s16x8*)&Xs[r * XS_STRIDE + k0]     = p0;
        *(s16x8*)&Xs[r * XS_STRIDE + k0 + 8] = p1;
    }

    const int w    = t >> 6;
    const int lane = t & 63;
    const int m    = lane & 15;
    const int q    = lane >> 4;

    s16x8 bfr[4];
#pragma unroll
    for (int kb = 0; kb < 4; ++kb)
        bfr[kb] = *(const s16x8*)(WTb + (size_t)(w * 16 + m) * IN_FEATS + kb * 32 + q * 8);

    const float al = attn_l[w * OUT_FEATS + m];
    const float ar = attn_r[w * OUT_FEATS + m];

    __syncthreads();

#pragma unroll
    for (int rg = 0; rg < 2; ++rg) {
        f32x4 acc = {0.f, 0.f, 0.f, 0.f};
#pragma unroll
        for (int kb = 0; kb < 4; ++kb) {
            const s16x8 af = *(const s16x8*)&Xs[(rg * 16 + m) * XS_STRIDE + kb * 32 + q * 8];
            acc = __builtin_amdgcn_mfma_f32_16x16x32_bf16(af, bfr[kb], acc, 0, 0, 0);
        }
#pragma unroll
        for (int r = 0; r < 4; ++r) {
            const int row = row0 + rg * 16 + q * 4 + r;
            featb[(size_t)row * HD + w * 16 + m] = __float2bfloat16(acc[r]);
            float cl = acc[r] * al;
            float cr = acc[r] * ar;
#pragma unroll
            for (int msk = 1; msk < 16; msk <<= 1) {
                cl += __shfl_xor(cl, msk, 64);
                cr += __shfl_xor(cr, msk, 64);
            }
            if (m == 0) {
                el[row * HEADS + w] = cl;
                eriz[(size_t)row * 8 + w] = cr;
            }
        }
    }
}

// ---------------------------------------------------------------------------
// Scatter: per-block LDS histogram, one global atomicAdd per (block,bucket)
// claims a run in bucket j's fixed region, LDS-cursor scatter. bu/ld cached
// in registers between passes.
// ---------------------------------------------------------------------------
__global__ __launch_bounds__(256) void scatter_kernel(
    const int* __restrict__ src, const int* __restrict__ dst,
    const int* __restrict__ etype,
    int* __restrict__ cnt, int* __restrict__ sc_bucket)
{
    __shared__ int h[NBUCK];
    int buld[16];                      // EPB/256 = 15.625 -> <=16 iters
    const int t = threadIdx.x, b = blockIdx.x;
    for (int j = t; j < NBUCK; j += 256) h[j] = 0;
    __syncthreads();
    const int e0 = b * EPB;
    int k = 0;
    for (int i = t; i < EPB; i += 256, ++k) {
        const int dn = dst[e0 + i];
        const int bu = dn / NPB;
        const int ld = dn - bu * NPB;
        buld[k] = bu | (ld << 16);
        atomicAdd(&h[bu], 1);
    }
    __syncthreads();
    for (int j = t; j < NBUCK; j += 256) {
        const int c = h[j];
        h[j] = j * BCAP + (c ? atomicAdd(&cnt[j], c) : 0);  // region cursor
    }
    __syncthreads();
    k = 0;
    for (int i = t; i < EPB; i += 256, ++k) {
        const int e  = e0 + i;
        const int bu = buld[k] & 0xFFFF;
        const int ld = buld[k] >> 16;
        const int slot = atomicAdd(&h[bu], 1);
        sc_bucket[slot] = src[e] | (etype[e] << 17) | (ld << 19);
    }
}

// ---------------------------------------------------------------------------
// CSR finalize: one block per bucket; redundant prefix of cnt; 4 per-wave
// LDS histograms; emit ptr + packed sc_csr {src | ty<<17}.
// ---------------------------------------------------------------------------
__global__ __launch_bounds__(256) void bucket_csr_kernel(
    const int* __restrict__ sc_bucket, const int* __restrict__ cnt,
    int* __restrict__ ptr, int* __restrict__ sc_csr)
{
    __shared__ int sbuf[BCAP];        // 10 KB
    __shared__ int sdeg4[4][128];     // per-wave hists, 2 KB
    __shared__ int sdg[128];
    __shared__ int scur[128];
    __shared__ int red[4];
    const int t = threadIdx.x, b = blockIdx.x;
    const int wid = t >> 6;

    int acc = 0;
    for (int j = t; j < b; j += 256) acc += cnt[j];
#pragma unroll
    for (int m = 1; m < 64; m <<= 1) acc += __shfl_xor(acc, m, 64);
    if ((t & 63) == 0) red[wid] = acc;
    sdeg4[0][t & 127] = 0; sdeg4[1][t & 127] = 0;
    if (t < 128) { sdeg4[2][t] = 0; sdeg4[3][t] = 0; }
    __syncthreads();
    const int lo    = red[0] + red[1] + red[2] + red[3];
    const int count = cnt[b];
    const int base  = b * BCAP;
    const bool staged = (count <= BCAP);

    if (staged) {
        for (int i = t; i < count; i += 256) {
            const int v = sc_bucket[base + i];
            sbuf[i] = v;
            atomicAdd(&sdeg4[wid][(v >> 19) & 0x7F], 1);
        }
    } else {
        for (int i = t; i < count; i += 256)
            atomicAdd(&sdeg4[wid][(sc_bucket[base + i] >> 19) & 0x7F], 1);
    }
    __syncthreads();
    int orig = 0;
    if (t < 128) {
        orig = sdeg4[0][t] + sdeg4[1][t] + sdeg4[2][t] + sdeg4[3][t];
        sdg[t] = orig;
    }
    __syncthreads();
    for (int off = 1; off < 128; off <<= 1) {
        const int v = (t < 128 && t >= off) ? sdg[t - off] : 0;
        __syncthreads();
        if (t < 128) sdg[t] += v;
        __syncthreads();
    }
    if (t < 128) {
        const int excl = sdg[t] - orig;
        if (t < NPB) ptr[b * NPB + t] = lo + excl;
        scur[t] = lo + excl;
    }
    if (b == 0 && t == 0) ptr[N_NODES] = N_EDGES;
    __syncthreads();
    if (staged) {
        for (int i = t; i < count; i += 256) {
            const int v = sbuf[i];
            const int ld = (v >> 19) & 0x7F;
            const int slot = atomicAdd(&scur[ld], 1);
            sc_csr[slot] = v & 0x7FFFF;
        }
    } else {
        for (int i = t; i < count; i += 256) {
            const int v = sc_bucket[base + i];
            const int ld = (v >> 19) & 0x7F;
            const int slot = atomicAdd(&scur[ld], 1);
            sc_csr[slot] = v & 0x7FFFF;
        }
    }
}

// ---------------------------------------------------------------------------
// Kernel C: per-dst aggregation, one wave per node, two in-wave phases.
// ROUND 7: both phases software-pipelined x2 for memory-level parallelism —
// 2 independent gather chains in flight per lane (was 1; VALUBusy 55% ->
// latency-bound diagnosis).
// ---------------------------------------------------------------------------
__global__ __launch_bounds__(256) void agg_kernel(
    const int* __restrict__ sc_csr, const int* __restrict__ ptr,
    const float* __restrict__ el, float* __restrict__ eriz,
    const float* __restrict__ ee, const __hip_bfloat16* __restrict__ featb,
    float* __restrict__ rst)
{
    __shared__ float w_lds[4][MAXD_LDS * HEADS];   // 8 KB
    __shared__ int   s_lds[4][MAXD_LDS];           // 2 KB
    const int wid  = threadIdx.x >> 6;
    const int lane = threadIdx.x & 63;
    const int n    = blockIdx.x * 4 + wid;

    const int p0  = ptr[n];
    const int deg = ptr[n + 1] - p0;
    float* wl = w_lds[wid];
    int*   sl = s_lds[wid];
    const ushort* fb = (const ushort*)featb;

    if (deg <= MAXD_LDS) {
        // ---- phase 1: weights, one lane per (edge, head), 32 edges/iter ----
        const int eo = lane >> 2;          // edge in group of 16
        const int hA = lane & 3;           // head
        const float er_n = eriz[(size_t)n * 8 + hA];
        const float g0 = ee[hA], g1 = ee[HEADS + hA], g2 = ee[2 * HEADS + hA];

        float zacc = 0.f;
        for (int i0 = 0; i0 < deg; i0 += 32) {
            const int idxA = i0 + eo;
            const int idxB = i0 + 16 + eo;
            const bool pA = idxA < deg;
            const bool pB = idxB < deg;
            int vA = 0, vB = 0;
            if (pA) vA = sc_csr[p0 + idxA];          // both loads issued
            if (pB) vB = sc_csr[p0 + idxB];
            float eA = 0.f, eB = 0.f;
            if (pA) eA = el[(vA & 0x1FFFF) * HEADS + hA];   // both gathers issued
            if (pB) eB = el[(vB & 0x1FFFF) * HEADS + hA];
            if (pA) {
                const int ty = vA >> 17;
                float s = eA + er_n + ((ty == 0) ? g0 : ((ty == 1) ? g1 : g2));
                s = s > 0.f ? s : NEG_SLOPE * s;
                const float w = __expf(s);
                wl[idxA * HEADS + hA] = w;
                if (hA == 0) sl[idxA] = vA & 0x1FFFF;
                zacc += w;
            }
            if (pB) {
                const int ty = vB >> 17;
                float s = eB + er_n + ((ty == 0) ? g0 : ((ty == 1) ? g1 : g2));
                s = s > 0.f ? s : NEG_SLOPE * s;
                const float w = __expf(s);
                wl[idxB * HEADS + hA] = w;
                if (hA == 0) sl[idxB] = vB & 0x1FFFF;
                zacc += w;
            }
        }
        // reduce z over edge groups (lane bits 2..5); lane then holds z[lane&3]
        zacc += __shfl_xor(zacc, 4, 64);
        zacc += __shfl_xor(zacc, 8, 64);
        zacc += __shfl_xor(zacc, 16, 64);
        zacc += __shfl_xor(zacc, 32, 64);
        if (lane < 4)
            eriz[(size_t)n * 8 + 4 + lane] = (deg > 0) ? __frcp_rn(zacc) : 0.f;

        // ---- phase 2: accumulate, 16 edges in flight (2 x 8-edge groups) ----
        const int q8 = lane >> 3;          // edge slot 0..7
        const int c8 = lane & 7;           // col group: cols 8*c8 .. 8*c8+7
        const int h8 = c8 >> 1;            // head of those cols
        const float inv_z = (deg > 0) ? __frcp_rn(__shfl(zacc, h8, 64)) : 0.f;

        float a0 = 0.f, a1 = 0.f, a2 = 0.f, a3 = 0.f;
        float a4 = 0.f, a5 = 0.f, a6 = 0.f, a7 = 0.f;
        int i = 0;
        for (; i + 16 <= deg; i += 16) {
            const int idxA = i + q8, idxB = i + 8 + q8;
            const int sA = sl[idxA], sB = sl[idxB];
            const float wA = wl[idxA * HEADS + h8];
            const float wB = wl[idxB * HEADS + h8];
            const uint4 fA = *(const uint4*)(fb + ((size_t)sA << 6) + (c8 << 3));
            const uint4 fB = *(const uint4*)(fb + ((size_t)sB << 6) + (c8 << 3));
            a0 += __uint_as_float(fA.x << 16) * wA;
            a1 += __uint_as_float(fA.x & 0xFFFF0000u) * wA;
            a2 += __uint_as_float(fA.y << 16) * wA;
            a3 += __uint_as_float(fA.y & 0xFFFF0000u) * wA;
            a4 += __uint_as_float(fA.z << 16) * wA;
            a5 += __uint_as_float(fA.z & 0xFFFF0000u) * wA;
            a6 += __uint_as_float(fA.w << 16) * wA;
            a7 += __uint_as_float(fA.w & 0xFFFF0000u) * wA;
            a0 += __uint_as_float(fB.x << 16) * wB;
            a1 += __uint_as_float(fB.x & 0xFFFF0000u) * wB;
            a2 += __uint_as_float(fB.y << 16) * wB;
            a3 += __uint_as_float(fB.y & 0xFFFF0000u) * wB;
            a4 += __uint_as_float(fB.z << 16) * wB;
            a5 += __uint_as_float(fB.z & 0xFFFF0000u) * wB;
            a6 += __uint_as_float(fB.w << 16) * wB;
            a7 += __uint_as_float(fB.w & 0xFFFF0000u) * wB;
        }
        if (i + 8 <= deg) {
            const int idx = i + q8;
            const int sA = sl[idx];
            const float wA = wl[idx * HEADS + h8];
            const uint4 fA = *(const uint4*)(fb + ((size_t)sA << 6) + (c8 << 3));
            a0 += __uint_as_float(fA.x << 16) * wA;
            a1 += __uint_as_float(fA.x & 0xFFFF0000u) * wA;
            a2 += __uint_as_float(fA.y << 16) * wA;
            a3 += __uint_as_float(fA.y & 0xFFFF0000u) * wA;
            a4 += __uint_as_float(fA.z << 16) * wA;
            a5 += __uint_as_float(fA.z & 0xFFFF0000u) * wA;
            a6 += __uint_as_float(fA.w << 16) * wA;
            a7 += __uint_as_float(fA.w & 0xFFFF0000u) * wA;
            i += 8;
        }
        if (i + q8 < deg) {                // tail (<8 edges), one guarded step
            const int idx = i + q8;
            const int sA = sl[idx];
            const float wA = wl[idx * HEADS + h8];
            const uint4 fA = *(const uint4*)(fb + ((size_t)sA << 6) + (c8 << 3));
            a0 += __uint_as_float(fA.x << 16) * wA;
            a1 += __uint_as_float(fA.x & 0xFFFF0000u) * wA;
            a2 += __uint_as_float(fA.y << 16) * wA;
            a3 += __uint_as_float(fA.y & 0xFFFF0000u) * wA;
            a4 += __uint_as_float(fA.z << 16) * wA;
            a5 += __uint_as_float(fA.z & 0xFFFF0000u) * wA;
            a6 += __uint_as_float(fA.w << 16) * wA;
            a7 += __uint_as_float(fA.w & 0xFFFF0000u) * wA;
        }
        // reduce over the 8 edge slots (lane bits 3..5)
        a0 += __shfl_xor(a0, 8, 64); a0 += __shfl_xor(a0, 16, 64); a0 += __shfl_xor(a0, 32, 64);
        a1 += __shfl_xor(a1, 8, 64); a1 += __shfl_xor(a1, 16, 64); a1 += __shfl_xor(a1, 32, 64);
        a2 += __shfl_xor(a2, 8, 64); a2 += __shfl_xor(a2, 16, 64); a2 += __shfl_xor(a2, 32, 64);
        a3 += __shfl_xor(a3, 8, 64); a3 += __shfl_xor(a3, 16, 64); a3 += __shfl_xor(a3, 32, 64);
        a4 += __shfl_xor(a4, 8, 64); a4 += __shfl_xor(a4, 16, 64); a4 += __shfl_xor(a4, 32, 64);
        a5 += __shfl_xor(a5, 8, 64); a5 += __shfl_xor(a5, 16, 64); a5 += __shfl_xor(a5, 32, 64);
        a6 += __shfl_xor(a6, 8, 64); a6 += __shfl_xor(a6, 16, 64); a6 += __shfl_xor(a6, 32, 64);
        a7 += __shfl_xor(a7, 8, 64); a7 += __shfl_xor(a7, 16, 64); a7 += __shfl_xor(a7, 32, 64);
        if (q8 == 0) {
            f32x4 v0 = {a0 * inv_z, a1 * inv_z, a2 * inv_z, a3 * inv_z};
            f32x4 v1 = {a4 * inv_z, a5 * inv_z, a6 * inv_z, a7 * inv_z};
            *(f32x4*)(rst + (size_t)n * HD + (c8 << 3))     = v0;
            *(f32x4*)(rst + (size_t)n * HD + (c8 << 3) + 4) = v1;
        }
    } else {
        // ---- rare big-degree path: two passes, recompute ----
        const int hA = lane & 3;
        const int eo = lane >> 2;
        const float er_nA = eriz[(size_t)n * 8 + hA];
        const float a0 = ee[hA], a1 = ee[HEADS + hA], a2 = ee[2 * HEADS + hA];
        float zacc = 0.f;
        for (int base = 0; base < deg; base += 16) {
            const int idx = base + eo;
            if (idx < deg) {
                const int v  = sc_csr[p0 + idx];
                const int sn = v & 0x1FFFF;
                const int ty = v >> 17;
                float s = el[sn * HEADS + hA] + er_nA + ((ty == 0) ? a0 : ((ty == 1) ? a1 : a2));
                s = s > 0.f ? s : NEG_SLOPE * s;
                zacc += __expf(s);
            }
        }
#pragma unroll
        for (int m = 4; m < 64; m <<= 1) zacc += __shfl_xor(zacc, m, 64);
        if (lane < 4) eriz[(size_t)n * 8 + 4 + lane] = __frcp_rn(zacc);
        const int h = lane >> 4;
        const float inv_z = __frcp_rn(__shfl(zacc, h, 64));
        const float er_n = eriz[(size_t)n * 8 + h];
        const float g0 = ee[h], g1 = ee[HEADS + h], g2 = ee[2 * HEADS + h];
        float racc = 0.f;
        for (int i = 0; i < deg; ++i) {
            const int v  = sc_csr[p0 + i];
            const int sn = v & 0x1FFFF;
            const int ty = v >> 17;
            float s = el[sn * HEADS + h] + er_n + ((ty == 0) ? g0 : ((ty == 1) ? g1 : g2));
            s = s > 0.f ? s : NEG_SLOPE * s;
            const float a = __expf(s) * inv_z;
            racc += __bfloat162float(featb[(size_t)sn * HD + lane]) * a;
        }
        rst[(size_t)n * HD + lane] = racc;
    }
}

// ---------------------------------------------------------------------------
// Kernel D: a_out in ORIGINAL edge order — fully coalesced float4 writes.
// ---------------------------------------------------------------------------
__global__ __launch_bounds__(256) void attn_out_kernel(
    const int* __restrict__ src, const int* __restrict__ dst,
    const int* __restrict__ etype,
    const float* __restrict__ el, const float* __restrict__ eriz,
    const float* __restrict__ ee,
    float* __restrict__ a_out)
{
    const int e = blockIdx.x * 256 + threadIdx.x;   // grid exact: E/256
    const int sN = src[e];
    const int dN = dst[e];
    const int ty = etype[e];
    const float4 l4 = *(const float4*)(el + (size_t)sN * HEADS);
    const float4 r4 = *(const float4*)(eriz + (size_t)dN * 8);
    const float4 iz = *(const float4*)(eriz + (size_t)dN * 8 + 4);
    const float4 g4 = *(const float4*)(ee + (size_t)ty * HEADS);
    float4 a;
    float s;
    s = l4.x + r4.x + g4.x; s = s > 0.f ? s : NEG_SLOPE * s; a.x = __expf(s) * iz.x;
    s = l4.y + r4.y + g4.y; s = s > 0.f ? s : NEG_SLOPE * s; a.y = __expf(s) * iz.y;
    s = l4.z + r4.z + g4.z; s = s > 0.f ? s : NEG_SLOPE * s; a.z = __expf(s) * iz.z;
    s = l4.w + r4.w + g4.w; s = s > 0.f ? s : NEG_SLOPE * s; a.w = __expf(s) * iz.w;
    *(float4*)(a_out + (size_t)e * HEADS) = a;
}

extern "C" void kernel_launch(void* const* d_in, const int* in_sizes, int n_in,
                              void* d_out, int out_size, void* d_ws, size_t ws_size,
                              hipStream_t stream)
{
    const float* x        = (const float*)d_in[0];
    const float* W        = (const float*)d_in[1];
    const float* W_e      = (const float*)d_in[2];
    const float* attn_l   = (const float*)d_in[3];
    const float* attn_r   = (const float*)d_in[4];
    const float* attn_e   = (const float*)d_in[5];
    const float* edge_emb = (const float*)d_in[6];
    const int* src   = (const int*)d_in[7];
    const int* dst   = (const int*)d_in[8];
    const int* etype = (const int*)d_in[9];

    float* out     = (float*)d_out;
    float* rst_out = out;                              // N*H*D
    float* a_out   = out + (size_t)N_NODES * HD;       // E*H

    char* w = (char*)d_ws;
    __hip_bfloat16* featb = (__hip_bfloat16*)w; w += (size_t)N_NODES * HD * 2;   // 12.8 MB
    float* el    = (float*)w;  w += (size_t)N_NODES * HEADS * 4;    //  1.6 MB
    float* eriz  = (float*)w;  w += (size_t)N_NODES * 8 * 4;        //  3.2 MB (er|invz)
    float* ee    = (float*)w;  w += 64;
    int*   ptr   = (int*)w;    w += (size_t)(N_NODES + 4) * 4;      //  0.4 MB
    int*   cnt   = (int*)w;    w += (size_t)(NBUCK + 8) * 4;        //  3.2 KB
    short* WTb   = (short*)w;  w += (size_t)HD * IN_FEATS * 2;      //   16 KB
    int*   sc_bucket = (int*)w; w += (size_t)NBUCK * BCAP * 4;      //  8.2 MB (fixed regions)
    int*   sc_csr    = (int*)w; w += (size_t)N_EDGES * 4;           //  6.4 MB (packed)
    // total ~32.6 MB

    wt_prep_kernel<<<(IN_FEATS * HD) / 256, 256, 0, stream>>>(W, WTb);
    feat_el_er_kernel<<<N_NODES / FROWS + 1, 256, 0, stream>>>(
        x, WTb, attn_l, attn_r, edge_emb, W_e, attn_e, featb, el, eriz, ee, cnt);
    scatter_kernel<<<PBLK, 256, 0, stream>>>(src, dst, etype, cnt, sc_bucket);
    bucket_csr_kernel<<<NBUCK, 256, 0, stream>>>(sc_bucket, cnt, ptr, sc_csr);
    agg_kernel<<<N_NODES / 4, 256, 0, stream>>>(
        sc_csr, ptr, el, eriz, ee, featb, rst_out);
    attn_out_kernel<<<N_EDGES / 256, 256, 0, stream>>>(
        src, dst, etype, el, eriz, ee, a_out);
}

// Round 9
// 259.989 us; speedup vs baseline: 2.6058x; 1.0625x over previous
//
#include <hip/hip_runtime.h>
#include <hip/hip_bf16.h>

#define N_NODES   100000
#define N_EDGES   1600000
#define N_ETYPES  3
#define IN_FEATS  128
#define HEADS     4
#define OUT_FEATS 16
#define EDGE_FEATS 64
#define HD        64            // HEADS*OUT_FEATS
#define NEG_SLOPE 0.2f
#define MAXD_LDS  128           // agg fast-path max degree (Poisson(16): P(>128)~0)

#define NBUCK     800           // buckets for counting sort
#define NPB       125           // nodes per bucket (800*125 = N_NODES)
#define PBLK      400           // blocks in scatter pass
#define EPB       4000          // edges per block (400*4000 = N_EDGES)
#define BCAP      2560          // fixed bucket-region capacity (mean 2000, 12.5 sigma)
#define FROWS     32            // rows per feat block (100000/32 = 3125 exact)

// sc_bucket payload (int2): {src, e | ty<<21 | ld<<23}  (e:21b ty:2b ld:7b)
// after csr in-place rebin:  {src, e | ty<<21}

typedef short s16x8 __attribute__((ext_vector_type(8)));
typedef float f32x4 __attribute__((ext_vector_type(4)));

__device__ __forceinline__ short f2bs(float f) {
    __hip_bfloat16 h = __float2bfloat16(f);
    return *reinterpret_cast<short*>(&h);
}

// ---------------------------------------------------------------------------
// Prep: WT bf16 [64][128]  (WT[n][k] = W[k][n])
// ---------------------------------------------------------------------------
__global__ __launch_bounds__(256) void wt_prep_kernel(
    const float* __restrict__ W, short* __restrict__ WTb)
{
    const int t = blockIdx.x * 256 + threadIdx.x;   // 0..8191
    const int k = t >> 6, n = t & 63;
    WTb[n * IN_FEATS + k] = f2bs(W[t]);
}

// ---------------------------------------------------------------------------
// Kernel A (MFMA): feat = x @ W, bf16 store, fused el/er.
// 32 rows/block; B-fragments direct from WTb (L1-resident). Service block
// zeroes cnt + computes ee.
// ---------------------------------------------------------------------------
#define XS_STRIDE 136   // 128 + 8 pad shorts
__global__ __launch_bounds__(256) void feat_el_er_kernel(
    const float* __restrict__ x,
    const short* __restrict__ WTb,
    const float* __restrict__ attn_l,
    const float* __restrict__ attn_r,
    const float* __restrict__ edge_emb,
    const float* __restrict__ W_e,
    const float* __restrict__ attn_e,
    __hip_bfloat16* __restrict__ featb,
    float* __restrict__ el,
    float* __restrict__ er,
    float* __restrict__ ee,
    int* __restrict__ cnt)
{
    const int t = threadIdx.x;

    if (blockIdx.x == N_NODES / FROWS) {
        // ---- service block: zero cnt + compute ee (12 jobs over 4 waves) ----
        for (int j = t; j < NBUCK; j += 256) cnt[j] = 0;
        const int wv = t >> 6, e = t & 63;
        for (int j = wv; j < N_ETYPES * HEADS; j += 4) {
            const int ty = j >> 2, h = j & 3;
            float ef = 0.f;
#pragma unroll
            for (int k = 0; k < EDGE_FEATS; ++k)
                ef += edge_emb[ty * EDGE_FEATS + k] *
                      W_e[k * (HEADS * EDGE_FEATS) + h * EDGE_FEATS + e];
            float v = ef * attn_e[h * EDGE_FEATS + e];
#pragma unroll
            for (int m = 1; m < 64; m <<= 1) v += __shfl_xor(v, m, 64);
            if (e == 0) ee[ty * HEADS + h] = v;
        }
        return;
    }

    __shared__ short Xs[FROWS * XS_STRIDE];   // 8.7 KB

    const int row0 = blockIdx.x * FROWS;
    {   // stage x -> bf16 LDS: 16 elems/thread
        const int r = t >> 3, k0 = (t & 7) * 16;
        const float4* xg = (const float4*)(x + (size_t)(row0 + r) * IN_FEATS + k0);
        const float4 v0 = xg[0], v1 = xg[1], v2 = xg[2], v3 = xg[3];
        s16x8 p0, p1;
        p0[0] = f2bs(v0.x); p0[1] = f2bs(v0.y); p0[2] = f2bs(v0.z); p0[3] = f2bs(v0.w);
        p0[4] = f2bs(v1.x); p0[5] = f2bs(v1.y); p0[6] = f2bs(v1.z); p0[7] = f2bs(v1.w);
        p1[0] = f2bs(v2.x); p1[1] = f2bs(v2.y); p1[2] = f2bs(v2.z); p1[3] = f2bs(v2.w);
        p1[4] = f2bs(v3.x); p1[5] = f2bs(v3.y); p1[6] = f2bs(v3.z); p1[7] = f2bs(v3.w);
        *(s16x8*)&Xs[r * XS_STRIDE + k0]     = p0;
        *(s16x8*)&Xs[r * XS_STRIDE + k0 + 8] = p1;
    }

    const int w    = t >> 6;
    const int lane = t & 63;
    const int m    = lane & 15;
    const int q    = lane >> 4;

    s16x8 bfr[4];
#pragma unroll
    for (int kb = 0; kb < 4; ++kb)
        bfr[kb] = *(const s16x8*)(WTb + (size_t)(w * 16 + m) * IN_FEATS + kb * 32 + q * 8);

    const float al = attn_l[w * OUT_FEATS + m];
    const float ar = attn_r[w * OUT_FEATS + m];

    __syncthreads();

#pragma unroll
    for (int rg = 0; rg < 2; ++rg) {
        f32x4 acc = {0.f, 0.f, 0.f, 0.f};
#pragma unroll
        for (int kb = 0; kb < 4; ++kb) {
            const s16x8 af = *(const s16x8*)&Xs[(rg * 16 + m) * XS_STRIDE + kb * 32 + q * 8];
            acc = __builtin_amdgcn_mfma_f32_16x16x32_bf16(af, bfr[kb], acc, 0, 0, 0);
        }
#pragma unroll
        for (int r = 0; r < 4; ++r) {
            const int row = row0 + rg * 16 + q * 4 + r;
            featb[(size_t)row * HD + w * 16 + m] = __float2bfloat16(acc[r]);
            float cl = acc[r] * al;
            float cr = acc[r] * ar;
#pragma unroll
            for (int msk = 1; msk < 16; msk <<= 1) {
                cl += __shfl_xor(cl, msk, 64);
                cr += __shfl_xor(cr, msk, 64);
            }
            if (m == 0) {
                el[row * HEADS + w] = cl;
                er[row * HEADS + w] = cr;
            }
        }
    }
}

// ---------------------------------------------------------------------------
// Scatter: per-block LDS histogram, one global atomicAdd per (block,bucket)
// claims a run in bucket j's fixed region, LDS-cursor scatter of int2
// {src, e|ty<<21|ld<<23}. bu/ld cached in registers between passes.
// ---------------------------------------------------------------------------
__global__ __launch_bounds__(256) void scatter_kernel(
    const int* __restrict__ src, const int* __restrict__ dst,
    const int* __restrict__ etype,
    int* __restrict__ cnt, int2* __restrict__ sc_bucket)
{
    __shared__ int h[NBUCK];
    int buld[16];                      // EPB/256 = 15.625 -> <=16 iters
    const int t = threadIdx.x, b = blockIdx.x;
    for (int j = t; j < NBUCK; j += 256) h[j] = 0;
    __syncthreads();
    const int e0 = b * EPB;
    int k = 0;
    for (int i = t; i < EPB; i += 256, ++k) {
        const int dn = dst[e0 + i];
        const int bu = dn / NPB;
        const int ld = dn - bu * NPB;
        buld[k] = bu | (ld << 16);
        atomicAdd(&h[bu], 1);
    }
    __syncthreads();
    for (int j = t; j < NBUCK; j += 256) {
        const int c = h[j];
        h[j] = j * BCAP + (c ? atomicAdd(&cnt[j], c) : 0);  // region cursor
    }
    __syncthreads();
    k = 0;
    for (int i = t; i < EPB; i += 256, ++k) {
        const int e  = e0 + i;
        const int bu = buld[k] & 0xFFFF;
        const int ld = buld[k] >> 16;
        const int slot = atomicAdd(&h[bu], 1);
        sc_bucket[slot] = make_int2(src[e], e | (etype[e] << 21) | (ld << 23));
    }
}

// ---------------------------------------------------------------------------
// CSR finalize IN-PLACE: one block per bucket; full LDS stage, bin over 125
// local nodes, write back into the SAME fixed region (no packed sc_csr, no
// cross-bucket prefix). Emits ptr[n] (region offset) + deg[n].
// ---------------------------------------------------------------------------
__global__ __launch_bounds__(256) void bucket_csr_kernel(
    int2* __restrict__ sc_bucket, const int* __restrict__ cnt,
    int* __restrict__ ptr, int* __restrict__ deg)
{
    __shared__ int2 sbuf[BCAP];       // 20.5 KB
    __shared__ int sdeg4[4][128];     // per-wave hists, 2 KB
    __shared__ int sdg[128];
    __shared__ int scur[128];
    const int t = threadIdx.x, b = blockIdx.x;
    const int wid = t >> 6;

    sdeg4[0][t & 127] = 0; sdeg4[1][t & 127] = 0;
    if (t < 128) { sdeg4[2][t] = 0; sdeg4[3][t] = 0; }
    __syncthreads();
    const int count = min(cnt[b], BCAP);
    const int base  = b * BCAP;

    for (int i = t; i < count; i += 256) {
        const int2 v = sc_bucket[base + i];
        sbuf[i] = v;
        atomicAdd(&sdeg4[wid][(v.y >> 23) & 0x7F], 1);
    }
    __syncthreads();
    int orig = 0;
    if (t < 128) {
        orig = sdeg4[0][t] + sdeg4[1][t] + sdeg4[2][t] + sdeg4[3][t];
        sdg[t] = orig;
    }
    __syncthreads();
    for (int off = 1; off < 128; off <<= 1) {
        const int v = (t < 128 && t >= off) ? sdg[t - off] : 0;
        __syncthreads();
        if (t < 128) sdg[t] += v;
        __syncthreads();
    }
    if (t < 128) {
        const int excl = sdg[t] - orig;
        if (t < NPB) {
            ptr[b * NPB + t] = base + excl;
            deg[b * NPB + t] = orig;
        }
        scur[t] = base + excl;           // region-local slot base
    }
    __syncthreads();
    for (int i = t; i < count; i += 256) {
        const int2 v = sbuf[i];
        const int ld = (v.y >> 23) & 0x7F;
        const int slot = atomicAdd(&scur[ld], 1);
        sc_bucket[slot] = make_int2(v.x, v.y & 0x7FFFFF);   // {src, e|ty<<21}
    }
}

// ---------------------------------------------------------------------------
// Kernel C: per-dst aggregation + FUSED a_out, one wave per node.
// Phase 1 (x2 pipelined): exp ONCE per (e,h); w,src,ey -> LDS; z reduce.
// After the {4,8,16,32} butterfly every lane holds z[lane&3]; z[h] is
// broadcast from LANE h (NOT h<<3 — round-8 bug).
// Epilogue: a_out[ey*4+h] = w * inv_z (4 lanes -> one 16B granule per edge).
// Phase 2 (x2 pipelined): 8 edges x 8 lanes, 16B dwordx4 feat loads.
// ---------------------------------------------------------------------------
__global__ __launch_bounds__(256) void agg_kernel(
    const int2* __restrict__ sc_csr, const int* __restrict__ ptr,
    const int* __restrict__ deg_arr,
    const float* __restrict__ el, const float* __restrict__ er,
    const float* __restrict__ ee, const __hip_bfloat16* __restrict__ featb,
    float* __restrict__ rst, float* __restrict__ a_out)
{
    __shared__ float w_lds[4][MAXD_LDS * HEADS];   // 8 KB
    __shared__ int   s_lds[4][MAXD_LDS];           // 2 KB
    __shared__ int   e_lds[4][MAXD_LDS];           // 2 KB
    const int wid  = threadIdx.x >> 6;
    const int lane = threadIdx.x & 63;
    const int n    = blockIdx.x * 4 + wid;

    const int p0  = ptr[n];
    const int deg = deg_arr[n];
    float* wl = w_lds[wid];
    int*   sl = s_lds[wid];
    int*   elds = e_lds[wid];
    const ushort* fb = (const ushort*)featb;

    if (deg <= MAXD_LDS) {
        // ---- phase 1: weights, one lane per (edge, head), 32 edges/iter ----
        const int eo = lane >> 2;          // edge in group of 16
        const int hA = lane & 3;           // head
        const float er_n = er[n * HEADS + hA];
        const float g0 = ee[hA], g1 = ee[HEADS + hA], g2 = ee[2 * HEADS + hA];

        float zacc = 0.f;
        for (int i0 = 0; i0 < deg; i0 += 32) {
            const int idxA = i0 + eo;
            const int idxB = i0 + 16 + eo;
            const bool pA = idxA < deg;
            const bool pB = idxB < deg;
            int2 vA = make_int2(0, 0), vB = make_int2(0, 0);
            if (pA) vA = sc_csr[p0 + idxA];          // both loads issued
            if (pB) vB = sc_csr[p0 + idxB];
            float eA = 0.f, eB = 0.f;
            if (pA) eA = el[vA.x * HEADS + hA];      // both gathers issued
            if (pB) eB = el[vB.x * HEADS + hA];
            if (pA) {
                const int ty = vA.y >> 21;
                float s = eA + er_n + ((ty == 0) ? g0 : ((ty == 1) ? g1 : g2));
                s = s > 0.f ? s : NEG_SLOPE * s;
                const float w = __expf(s);
                wl[idxA * HEADS + hA] = w;
                if (hA == 0) sl[idxA] = vA.x;
                if (hA == 1) elds[idxA] = vA.y & 0x1FFFFF;
                zacc += w;
            }
            if (pB) {
                const int ty = vB.y >> 21;
                float s = eB + er_n + ((ty == 0) ? g0 : ((ty == 1) ? g1 : g2));
                s = s > 0.f ? s : NEG_SLOPE * s;
                const float w = __expf(s);
                wl[idxB * HEADS + hA] = w;
                if (hA == 0) sl[idxB] = vB.x;
                if (hA == 1) elds[idxB] = vB.y & 0x1FFFFF;
                zacc += w;
            }
        }
        // reduce z over edge groups (lane bits 2..5); every lane holds z[lane&3]
        zacc += __shfl_xor(zacc, 4, 64);
        zacc += __shfl_xor(zacc, 8, 64);
        zacc += __shfl_xor(zacc, 16, 64);
        zacc += __shfl_xor(zacc, 32, 64);
        const float izA = (deg > 0) ? __frcp_rn(zacc) : 0.f;

        // ---- a_out epilogue: 4 lanes (heads) write one 16B granule/edge ----
        for (int idx = eo; idx < deg; idx += 16)
            a_out[((size_t)elds[idx] << 2) + hA] = wl[idx * HEADS + hA] * izA;

        // ---- phase 2: accumulate, 16 edges in flight (2 x 8-edge groups) ----
        const int q8 = lane >> 3;          // edge slot 0..7
        const int c8 = lane & 7;           // col group: cols 8*c8 .. 8*c8+7
        const int h8 = c8 >> 1;            // head of those cols
        // z[h8] lives at lane h8 (lane&3 == h8 for lanes 0..3)
        const float inv_z = (deg > 0) ? __frcp_rn(__shfl(zacc, h8, 64)) : 0.f;

        float a0 = 0.f, a1 = 0.f, a2 = 0.f, a3 = 0.f;
        float a4 = 0.f, a5 = 0.f, a6 = 0.f, a7 = 0.f;
        int i = 0;
        for (; i + 16 <= deg; i += 16) {
            const int idxA = i + q8, idxB = i + 8 + q8;
            const int sA = sl[idxA], sB = sl[idxB];
            const float wA = wl[idxA * HEADS + h8];
            const float wB = wl[idxB * HEADS + h8];
            const uint4 fA = *(const uint4*)(fb + ((size_t)sA << 6) + (c8 << 3));
            const uint4 fB = *(const uint4*)(fb + ((size_t)sB << 6) + (c8 << 3));
            a0 += __uint_as_float(fA.x << 16) * wA;
            a1 += __uint_as_float(fA.x & 0xFFFF0000u) * wA;
            a2 += __uint_as_float(fA.y << 16) * wA;
            a3 += __uint_as_float(fA.y & 0xFFFF0000u) * wA;
            a4 += __uint_as_float(fA.z << 16) * wA;
            a5 += __uint_as_float(fA.z & 0xFFFF0000u) * wA;
            a6 += __uint_as_float(fA.w << 16) * wA;
            a7 += __uint_as_float(fA.w & 0xFFFF0000u) * wA;
            a0 += __uint_as_float(fB.x << 16) * wB;
            a1 += __uint_as_float(fB.x & 0xFFFF0000u) * wB;
            a2 += __uint_as_float(fB.y << 16) * wB;
            a3 += __uint_as_float(fB.y & 0xFFFF0000u) * wB;
            a4 += __uint_as_float(fB.z << 16) * wB;
            a5 += __uint_as_float(fB.z & 0xFFFF0000u) * wB;
            a6 += __uint_as_float(fB.w << 16) * wB;
            a7 += __uint_as_float(fB.w & 0xFFFF0000u) * wB;
        }
        if (i + 8 <= deg) {
            const int idx = i + q8;
            const int sA = sl[idx];
            const float wA = wl[idx * HEADS + h8];
            const uint4 fA = *(const uint4*)(fb + ((size_t)sA << 6) + (c8 << 3));
            a0 += __uint_as_float(fA.x << 16) * wA;
            a1 += __uint_as_float(fA.x & 0xFFFF0000u) * wA;
            a2 += __uint_as_float(fA.y << 16) * wA;
            a3 += __uint_as_float(fA.y & 0xFFFF0000u) * wA;
            a4 += __uint_as_float(fA.z << 16) * wA;
            a5 += __uint_as_float(fA.z & 0xFFFF0000u) * wA;
            a6 += __uint_as_float(fA.w << 16) * wA;
            a7 += __uint_as_float(fA.w & 0xFFFF0000u) * wA;
            i += 8;
        }
        if (i + q8 < deg) {                // tail (<8 edges), one guarded step
            const int idx = i + q8;
            const int sA = sl[idx];
            const float wA = wl[idx * HEADS + h8];
            const uint4 fA = *(const uint4*)(fb + ((size_t)sA << 6) + (c8 << 3));
            a0 += __uint_as_float(fA.x << 16) * wA;
            a1 += __uint_as_float(fA.x & 0xFFFF0000u) * wA;
            a2 += __uint_as_float(fA.y << 16) * wA;
            a3 += __uint_as_float(fA.y & 0xFFFF0000u) * wA;
            a4 += __uint_as_float(fA.z << 16) * wA;
            a5 += __uint_as_float(fA.z & 0xFFFF0000u) * wA;
            a6 += __uint_as_float(fA.w << 16) * wA;
            a7 += __uint_as_float(fA.w & 0xFFFF0000u) * wA;
        }
        // reduce over the 8 edge slots (lane bits 3..5)
        a0 += __shfl_xor(a0, 8, 64); a0 += __shfl_xor(a0, 16, 64); a0 += __shfl_xor(a0, 32, 64);
        a1 += __shfl_xor(a1, 8, 64); a1 += __shfl_xor(a1, 16, 64); a1 += __shfl_xor(a1, 32, 64);
        a2 += __shfl_xor(a2, 8, 64); a2 += __shfl_xor(a2, 16, 64); a2 += __shfl_xor(a2, 32, 64);
        a3 += __shfl_xor(a3, 8, 64); a3 += __shfl_xor(a3, 16, 64); a3 += __shfl_xor(a3, 32, 64);
        a4 += __shfl_xor(a4, 8, 64); a4 += __shfl_xor(a4, 16, 64); a4 += __shfl_xor(a4, 32, 64);
        a5 += __shfl_xor(a5, 8, 64); a5 += __shfl_xor(a5, 16, 64); a5 += __shfl_xor(a5, 32, 64);
        a6 += __shfl_xor(a6, 8, 64); a6 += __shfl_xor(a6, 16, 64); a6 += __shfl_xor(a6, 32, 64);
        a7 += __shfl_xor(a7, 8, 64); a7 += __shfl_xor(a7, 16, 64); a7 += __shfl_xor(a7, 32, 64);
        if (q8 == 0) {
            f32x4 v0 = {a0 * inv_z, a1 * inv_z, a2 * inv_z, a3 * inv_z};
            f32x4 v1 = {a4 * inv_z, a5 * inv_z, a6 * inv_z, a7 * inv_z};
            *(f32x4*)(rst + (size_t)n * HD + (c8 << 3))     = v0;
            *(f32x4*)(rst + (size_t)n * HD + (c8 << 3) + 4) = v1;
        }
    } else {
        // ---- rare big-degree path: two passes, recompute ----
        const int hA = lane & 3;
        const int eo = lane >> 2;
        const float er_nA = er[n * HEADS + hA];
        const float b0 = ee[hA], b1 = ee[HEADS + hA], b2 = ee[2 * HEADS + hA];
        float zacc = 0.f;
        for (int base = 0; base < deg; base += 16) {
            const int idx = base + eo;
            if (idx < deg) {
                const int2 v = sc_csr[p0 + idx];
                const int ty = v.y >> 21;
                float s = el[v.x * HEADS + hA] + er_nA + ((ty == 0) ? b0 : ((ty == 1) ? b1 : b2));
                s = s > 0.f ? s : NEG_SLOPE * s;
                zacc += __expf(s);
            }
        }
#pragma unroll
        for (int m = 4; m < 64; m <<= 1) zacc += __shfl_xor(zacc, m, 64);
        const int h = lane >> 4;
        const int d = lane & 15;
        // every lane holds z[lane&3]; z[h] lives at lane h
        const float inv_z = __frcp_rn(__shfl(zacc, h, 64));
        const float er_n = er[n * HEADS + h];
        const float g0 = ee[h], g1 = ee[HEADS + h], g2 = ee[2 * HEADS + h];
        float racc = 0.f;
        for (int i = 0; i < deg; ++i) {
            const int2 v = sc_csr[p0 + i];
            const int ty = v.y >> 21;
            float s = el[v.x * HEADS + h] + er_n + ((ty == 0) ? g0 : ((ty == 1) ? g1 : g2));
            s = s > 0.f ? s : NEG_SLOPE * s;
            const float a = __expf(s) * inv_z;
            racc += __bfloat162float(featb[(size_t)v.x * HD + lane]) * a;
            if (d == 0) a_out[((size_t)(v.y & 0x1FFFFF) << 2) + h] = a;
        }
        rst[(size_t)n * HD + lane] = racc;
    }
}

extern "C" void kernel_launch(void* const* d_in, const int* in_sizes, int n_in,
                              void* d_out, int out_size, void* d_ws, size_t ws_size,
                              hipStream_t stream)
{
    const float* x        = (const float*)d_in[0];
    const float* W        = (const float*)d_in[1];
    const float* W_e      = (const float*)d_in[2];
    const float* attn_l   = (const float*)d_in[3];
    const float* attn_r   = (const float*)d_in[4];
    const float* attn_e   = (const float*)d_in[5];
    const float* edge_emb = (const float*)d_in[6];
    const int* src   = (const int*)d_in[7];
    const int* dst   = (const int*)d_in[8];
    const int* etype = (const int*)d_in[9];

    float* out     = (float*)d_out;
    float* rst_out = out;                              // N*H*D
    float* a_out   = out + (size_t)N_NODES * HD;       // E*H

    char* w = (char*)d_ws;
    __hip_bfloat16* featb = (__hip_bfloat16*)w; w += (size_t)N_NODES * HD * 2;   // 12.8 MB
    float* el    = (float*)w;  w += (size_t)N_NODES * HEADS * 4;    //  1.6 MB
    float* er    = (float*)w;  w += (size_t)N_NODES * HEADS * 4;    //  1.6 MB
    float* ee    = (float*)w;  w += 64;
    int*   ptr   = (int*)w;    w += (size_t)(N_NODES + 8) * 4;      //  0.4 MB
    int*   deg   = (int*)w;    w += (size_t)(N_NODES + 8) * 4;      //  0.4 MB
    int*   cnt   = (int*)w;    w += (size_t)(NBUCK + 8) * 4;        //  3.2 KB
    short* WTb   = (short*)w;  w += (size_t)HD * IN_FEATS * 2;      //   16 KB
    int2*  sc_bucket = (int2*)w; w += ((size_t)NBUCK * BCAP + 2048) * 8;  // 16.4 MB
    // total ~33.3 MB (well under known-good 43 MB)

    wt_prep_kernel<<<(IN_FEATS * HD) / 256, 256, 0, stream>>>(W, WTb);
    feat_el_er_kernel<<<N_NODES / FROWS + 1, 256, 0, stream>>>(
        x, WTb, attn_l, attn_r, edge_emb, W_e, attn_e, featb, el, er, ee, cnt);
    scatter_kernel<<<PBLK, 256, 0, stream>>>(src, dst, etype, cnt, sc_bucket);
    bucket_csr_kernel<<<NBUCK, 256, 0, stream>>>(sc_bucket, cnt, ptr, deg);
    agg_kernel<<<N_NODES / 4, 256, 0, stream>>>(
        sc_bucket, ptr, deg, el, er, ee, featb, rst_out, a_out);
}

// Round 10
// 249.591 us; speedup vs baseline: 2.7143x; 1.0417x over previous
//
#include <hip/hip_runtime.h>
#include <hip/hip_bf16.h>

#define N_NODES   100000
#define N_EDGES   1600000
#define N_ETYPES  3
#define IN_FEATS  128
#define HEADS     4
#define OUT_FEATS 16
#define EDGE_FEATS 64
#define HD        64            // HEADS*OUT_FEATS
#define NEG_SLOPE 0.2f
#define MAXD_LDS  128           // agg fast-path max degree (Poisson(16): P(>128)~0)

#define NBUCK     800           // buckets for counting sort
#define NPB       125           // nodes per bucket (800*125 = N_NODES)
#define PBLK      400           // scatter blocks
#define EPB       4000          // edges per scatter block
#define BCAP      2560          // fixed bucket-region capacity (mean 2000, 12.5 sigma)
#define FROWS     32            // rows per feat block (100000/32 = 3125 exact)
#define NFEAT     (N_NODES / FROWS)   // 3125

// fused grid layout: [0, PBLK) scatter | PBLK service(ee) | (PBLK, PBLK+NFEAT] feat
// sc_bucket payload (int2): {src, e | ty<<21 | ld<<23}; after csr: {src, e | ty<<21}

typedef short s16x8 __attribute__((ext_vector_type(8)));
typedef float f32x4 __attribute__((ext_vector_type(4)));

__device__ __forceinline__ short f2bs(float f) {
    __hip_bfloat16 h = __float2bfloat16(f);
    return *reinterpret_cast<short*>(&h);
}

// ---------------------------------------------------------------------------
// Prep: WT bf16 [64][128] (WT[n][k] = W[k][n]); block 0 also zeroes cnt
// (must precede the fused kernel's scatter atomics — stream order).
// ---------------------------------------------------------------------------
__global__ __launch_bounds__(256) void wt_prep_kernel(
    const float* __restrict__ W, short* __restrict__ WTb, int* __restrict__ cnt)
{
    const int t = blockIdx.x * 256 + threadIdx.x;   // 0..8191
    const int k = t >> 6, n = t & 63;
    WTb[n * IN_FEATS + k] = f2bs(W[t]);
    if (blockIdx.x == 0)
        for (int j = threadIdx.x; j < NBUCK; j += 256) cnt[j] = 0;
}

// ---------------------------------------------------------------------------
// FUSED kernel: scatter (blocks < PBLK) runs CONCURRENTLY with the MFMA
// feat GEMM (blocks > PBLK) — independent data, complementary pipes
// (atomic/LDS vs MFMA/BW). Block PBLK computes ee.
// ---------------------------------------------------------------------------
#define XS_STRIDE 136   // 128 + 8 pad shorts
__global__ __launch_bounds__(256) void feat_scatter_kernel(
    const float* __restrict__ x,
    const short* __restrict__ WTb,
    const float* __restrict__ attn_l,
    const float* __restrict__ attn_r,
    const float* __restrict__ edge_emb,
    const float* __restrict__ W_e,
    const float* __restrict__ attn_e,
    const int* __restrict__ src, const int* __restrict__ dst,
    const int* __restrict__ etype,
    __hip_bfloat16* __restrict__ featb,
    float* __restrict__ el,
    float* __restrict__ er,
    float* __restrict__ ee,
    int* __restrict__ cnt, int2* __restrict__ sc_bucket)
{
    __shared__ __align__(16) char smem[FROWS * XS_STRIDE * 2];   // 8.7 KB union
    const int t = threadIdx.x;
    const int b = blockIdx.x;

    if (b < PBLK) {
        // ---- scatter path: LDS hist -> region claim -> LDS-cursor scatter ----
        int* h = (int*)smem;                 // NBUCK ints (3.2 KB of union)
        int buld[16];                        // EPB/256 = 15.625 -> <=16 iters
        for (int j = t; j < NBUCK; j += 256) h[j] = 0;
        __syncthreads();
        const int e0 = b * EPB;
        int k = 0;
        for (int i = t; i < EPB; i += 256, ++k) {
            const int dn = dst[e0 + i];
            const int bu = dn / NPB;
            const int ld = dn - bu * NPB;
            buld[k] = bu | (ld << 16);
            atomicAdd(&h[bu], 1);
        }
        __syncthreads();
        for (int j = t; j < NBUCK; j += 256) {
            const int c = h[j];
            h[j] = j * BCAP + (c ? atomicAdd(&cnt[j], c) : 0);  // region cursor
        }
        __syncthreads();
        k = 0;
        for (int i = t; i < EPB; i += 256, ++k) {
            const int e  = e0 + i;
            const int bu = buld[k] & 0xFFFF;
            const int ld = buld[k] >> 16;
            const int slot = atomicAdd(&h[bu], 1);
            sc_bucket[slot] = make_int2(src[e], e | (etype[e] << 21) | (ld << 23));
        }
        return;
    }

    if (b == PBLK) {
        // ---- service block: ee (12 jobs over 4 waves) ----
        const int wv = t >> 6, e = t & 63;
        for (int j = wv; j < N_ETYPES * HEADS; j += 4) {
            const int ty = j >> 2, h = j & 3;
            float ef = 0.f;
#pragma unroll
            for (int k = 0; k < EDGE_FEATS; ++k)
                ef += edge_emb[ty * EDGE_FEATS + k] *
                      W_e[k * (HEADS * EDGE_FEATS) + h * EDGE_FEATS + e];
            float v = ef * attn_e[h * EDGE_FEATS + e];
#pragma unroll
            for (int m = 1; m < 64; m <<= 1) v += __shfl_xor(v, m, 64);
            if (e == 0) ee[ty * HEADS + h] = v;
        }
        return;
    }

    // ---- feat path: 32 rows/block MFMA GEMM + fused el/er ----
    short* Xs = (short*)smem;                // FROWS*XS_STRIDE shorts
    const int row0 = (b - PBLK - 1) * FROWS;
    {   // stage x -> bf16 LDS: 16 elems/thread
        const int r = t >> 3, k0 = (t & 7) * 16;
        const float4* xg = (const float4*)(x + (size_t)(row0 + r) * IN_FEATS + k0);
        const float4 v0 = xg[0], v1 = xg[1], v2 = xg[2], v3 = xg[3];
        s16x8 p0, p1;
        p0[0] = f2bs(v0.x); p0[1] = f2bs(v0.y); p0[2] = f2bs(v0.z); p0[3] = f2bs(v0.w);
        p0[4] = f2bs(v1.x); p0[5] = f2bs(v1.y); p0[6] = f2bs(v1.z); p0[7] = f2bs(v1.w);
        p1[0] = f2bs(v2.x); p1[1] = f2bs(v2.y); p1[2] = f2bs(v2.z); p1[3] = f2bs(v2.w);
        p1[4] = f2bs(v3.x); p1[5] = f2bs(v3.y); p1[6] = f2bs(v3.z); p1[7] = f2bs(v3.w);
        *(s16x8*)&Xs[r * XS_STRIDE + k0]     = p0;
        *(s16x8*)&Xs[r * XS_STRIDE + k0 + 8] = p1;
    }

    const int w    = t >> 6;
    const int lane = t & 63;
    const int m    = lane & 15;
    const int q    = lane >> 4;

    s16x8 bfr[4];
#pragma unroll
    for (int kb = 0; kb < 4; ++kb)
        bfr[kb] = *(const s16x8*)(WTb + (size_t)(w * 16 + m) * IN_FEATS + kb * 32 + q * 8);

    const float al = attn_l[w * OUT_FEATS + m];
    const float ar = attn_r[w * OUT_FEATS + m];

    __syncthreads();

#pragma unroll
    for (int rg = 0; rg < 2; ++rg) {
        f32x4 acc = {0.f, 0.f, 0.f, 0.f};
#pragma unroll
        for (int kb = 0; kb < 4; ++kb) {
            const s16x8 af = *(const s16x8*)&Xs[(rg * 16 + m) * XS_STRIDE + kb * 32 + q * 8];
            acc = __builtin_amdgcn_mfma_f32_16x16x32_bf16(af, bfr[kb], acc, 0, 0, 0);
        }
#pragma unroll
        for (int r = 0; r < 4; ++r) {
            const int row = row0 + rg * 16 + q * 4 + r;
            featb[(size_t)row * HD + w * 16 + m] = __float2bfloat16(acc[r]);
            float cl = acc[r] * al;
            float cr = acc[r] * ar;
#pragma unroll
            for (int msk = 1; msk < 16; msk <<= 1) {
                cl += __shfl_xor(cl, msk, 64);
                cr += __shfl_xor(cr, msk, 64);
            }
            if (m == 0) {
                el[row * HEADS + w] = cl;
                er[row * HEADS + w] = cr;
            }
        }
    }
}

// ---------------------------------------------------------------------------
// CSR finalize IN-PLACE: one block per bucket; full LDS stage, bin over 125
// local nodes, write back into the SAME fixed region. Emits ptr[n] + deg[n].
// ---------------------------------------------------------------------------
__global__ __launch_bounds__(256) void bucket_csr_kernel(
    int2* __restrict__ sc_bucket, const int* __restrict__ cnt,
    int* __restrict__ ptr, int* __restrict__ deg)
{
    __shared__ int2 sbuf[BCAP];       // 20.5 KB
    __shared__ int sdeg4[4][128];     // per-wave hists, 2 KB
    __shared__ int sdg[128];
    __shared__ int scur[128];
    const int t = threadIdx.x, b = blockIdx.x;
    const int wid = t >> 6;

    sdeg4[0][t & 127] = 0; sdeg4[1][t & 127] = 0;
    if (t < 128) { sdeg4[2][t] = 0; sdeg4[3][t] = 0; }
    __syncthreads();
    const int count = min(cnt[b], BCAP);
    const int base  = b * BCAP;

    for (int i = t; i < count; i += 256) {
        const int2 v = sc_bucket[base + i];
        sbuf[i] = v;
        atomicAdd(&sdeg4[wid][(v.y >> 23) & 0x7F], 1);
    }
    __syncthreads();
    int orig = 0;
    if (t < 128) {
        orig = sdeg4[0][t] + sdeg4[1][t] + sdeg4[2][t] + sdeg4[3][t];
        sdg[t] = orig;
    }
    __syncthreads();
    for (int off = 1; off < 128; off <<= 1) {
        const int v = (t < 128 && t >= off) ? sdg[t - off] : 0;
        __syncthreads();
        if (t < 128) sdg[t] += v;
        __syncthreads();
    }
    if (t < 128) {
        const int excl = sdg[t] - orig;
        if (t < NPB) {
            ptr[b * NPB + t] = base + excl;
            deg[b * NPB + t] = orig;
        }
        scur[t] = base + excl;           // region-local slot base
    }
    __syncthreads();
    for (int i = t; i < count; i += 256) {
        const int2 v = sbuf[i];
        const int ld = (v.y >> 23) & 0x7F;
        const int slot = atomicAdd(&scur[ld], 1);
        sc_bucket[slot] = make_int2(v.x, v.y & 0x7FFFFF);   // {src, e|ty<<21}
    }
}

// ---------------------------------------------------------------------------
// Kernel C: per-dst aggregation + FUSED a_out, one wave per node.
// Phase 1 (x2 pipelined): exp ONCE per (e,h); w,src,ey -> LDS; z reduce.
// After the {4,8,16,32} butterfly every lane holds z[lane&3]; z[h] broadcast
// from LANE h. Epilogue: a_out[ey*4+h] = w*inv_z (16B granule per edge).
// Phase 2 (x2 pipelined): 8 edges x 8 lanes, 16B dwordx4 feat loads.
// ---------------------------------------------------------------------------
__global__ __launch_bounds__(256) void agg_kernel(
    const int2* __restrict__ sc_csr, const int* __restrict__ ptr,
    const int* __restrict__ deg_arr,
    const float* __restrict__ el, const float* __restrict__ er,
    const float* __restrict__ ee, const __hip_bfloat16* __restrict__ featb,
    float* __restrict__ rst, float* __restrict__ a_out)
{
    __shared__ float w_lds[4][MAXD_LDS * HEADS];   // 8 KB
    __shared__ int   s_lds[4][MAXD_LDS];           // 2 KB
    __shared__ int   e_lds[4][MAXD_LDS];           // 2 KB
    const int wid  = threadIdx.x >> 6;
    const int lane = threadIdx.x & 63;
    const int n    = blockIdx.x * 4 + wid;

    const int p0  = ptr[n];
    const int deg = deg_arr[n];
    float* wl = w_lds[wid];
    int*   sl = s_lds[wid];
    int*   elds = e_lds[wid];
    const ushort* fb = (const ushort*)featb;

    if (deg <= MAXD_LDS) {
        // ---- phase 1: weights, one lane per (edge, head), 32 edges/iter ----
        const int eo = lane >> 2;          // edge in group of 16
        const int hA = lane & 3;           // head
        const float er_n = er[n * HEADS + hA];
        const float g0 = ee[hA], g1 = ee[HEADS + hA], g2 = ee[2 * HEADS + hA];

        float zacc = 0.f;
        for (int i0 = 0; i0 < deg; i0 += 32) {
            const int idxA = i0 + eo;
            const int idxB = i0 + 16 + eo;
            const bool pA = idxA < deg;
            const bool pB = idxB < deg;
            int2 vA = make_int2(0, 0), vB = make_int2(0, 0);
            if (pA) vA = sc_csr[p0 + idxA];          // both loads issued
            if (pB) vB = sc_csr[p0 + idxB];
            float eA = 0.f, eB = 0.f;
            if (pA) eA = el[vA.x * HEADS + hA];      // both gathers issued
            if (pB) eB = el[vB.x * HEADS + hA];
            if (pA) {
                const int ty = vA.y >> 21;
                float s = eA + er_n + ((ty == 0) ? g0 : ((ty == 1) ? g1 : g2));
                s = s > 0.f ? s : NEG_SLOPE * s;
                const float w = __expf(s);
                wl[idxA * HEADS + hA] = w;
                if (hA == 0) sl[idxA] = vA.x;
                if (hA == 1) elds[idxA] = vA.y & 0x1FFFFF;
                zacc += w;
            }
            if (pB) {
                const int ty = vB.y >> 21;
                float s = eB + er_n + ((ty == 0) ? g0 : ((ty == 1) ? g1 : g2));
                s = s > 0.f ? s : NEG_SLOPE * s;
                const float w = __expf(s);
                wl[idxB * HEADS + hA] = w;
                if (hA == 0) sl[idxB] = vB.x;
                if (hA == 1) elds[idxB] = vB.y & 0x1FFFFF;
                zacc += w;
            }
        }
        // reduce z over edge groups (lane bits 2..5); every lane holds z[lane&3]
        zacc += __shfl_xor(zacc, 4, 64);
        zacc += __shfl_xor(zacc, 8, 64);
        zacc += __shfl_xor(zacc, 16, 64);
        zacc += __shfl_xor(zacc, 32, 64);
        const float izA = (deg > 0) ? __frcp_rn(zacc) : 0.f;

        // ---- a_out epilogue: 4 lanes (heads) write one 16B granule/edge ----
        for (int idx = eo; idx < deg; idx += 16)
            a_out[((size_t)elds[idx] << 2) + hA] = wl[idx * HEADS + hA] * izA;

        // ---- phase 2: accumulate, 16 edges in flight (2 x 8-edge groups) ----
        const int q8 = lane >> 3;          // edge slot 0..7
        const int c8 = lane & 7;           // col group: cols 8*c8 .. 8*c8+7
        const int h8 = c8 >> 1;            // head of those cols
        // z[h8] lives at lane h8
        const float inv_z = (deg > 0) ? __frcp_rn(__shfl(zacc, h8, 64)) : 0.f;

        float a0 = 0.f, a1 = 0.f, a2 = 0.f, a3 = 0.f;
        float a4 = 0.f, a5 = 0.f, a6 = 0.f, a7 = 0.f;
        int i = 0;
        for (; i + 16 <= deg; i += 16) {
            const int idxA = i + q8, idxB = i + 8 + q8;
            const int sA = sl[idxA], sB = sl[idxB];
            const float wA = wl[idxA * HEADS + h8];
            const float wB = wl[idxB * HEADS + h8];
            const uint4 fA = *(const uint4*)(fb + ((size_t)sA << 6) + (c8 << 3));
            const uint4 fB = *(const uint4*)(fb + ((size_t)sB << 6) + (c8 << 3));
            a0 += __uint_as_float(fA.x << 16) * wA;
            a1 += __uint_as_float(fA.x & 0xFFFF0000u) * wA;
            a2 += __uint_as_float(fA.y << 16) * wA;
            a3 += __uint_as_float(fA.y & 0xFFFF0000u) * wA;
            a4 += __uint_as_float(fA.z << 16) * wA;
            a5 += __uint_as_float(fA.z & 0xFFFF0000u) * wA;
            a6 += __uint_as_float(fA.w << 16) * wA;
            a7 += __uint_as_float(fA.w & 0xFFFF0000u) * wA;
            a0 += __uint_as_float(fB.x << 16) * wB;
            a1 += __uint_as_float(fB.x & 0xFFFF0000u) * wB;
            a2 += __uint_as_float(fB.y << 16) * wB;
            a3 += __uint_as_float(fB.y & 0xFFFF0000u) * wB;
            a4 += __uint_as_float(fB.z << 16) * wB;
            a5 += __uint_as_float(fB.z & 0xFFFF0000u) * wB;
            a6 += __uint_as_float(fB.w << 16) * wB;
            a7 += __uint_as_float(fB.w & 0xFFFF0000u) * wB;
        }
        if (i + 8 <= deg) {
            const int idx = i + q8;
            const int sA = sl[idx];
            const float wA = wl[idx * HEADS + h8];
            const uint4 fA = *(const uint4*)(fb + ((size_t)sA << 6) + (c8 << 3));
            a0 += __uint_as_float(fA.x << 16) * wA;
            a1 += __uint_as_float(fA.x & 0xFFFF0000u) * wA;
            a2 += __uint_as_float(fA.y << 16) * wA;
            a3 += __uint_as_float(fA.y & 0xFFFF0000u) * wA;
            a4 += __uint_as_float(fA.z << 16) * wA;
            a5 += __uint_as_float(fA.z & 0xFFFF0000u) * wA;
            a6 += __uint_as_float(fA.w << 16) * wA;
            a7 += __uint_as_float(fA.w & 0xFFFF0000u) * wA;
            i += 8;
        }
        if (i + q8 < deg) {                // tail (<8 edges), one guarded step
            const int idx = i + q8;
            const int sA = sl[idx];
            const float wA = wl[idx * HEADS + h8];
            const uint4 fA = *(const uint4*)(fb + ((size_t)sA << 6) + (c8 << 3));
            a0 += __uint_as_float(fA.x << 16) * wA;
            a1 += __uint_as_float(fA.x & 0xFFFF0000u) * wA;
            a2 += __uint_as_float(fA.y << 16) * wA;
            a3 += __uint_as_float(fA.y & 0xFFFF0000u) * wA;
            a4 += __uint_as_float(fA.z << 16) * wA;
            a5 += __uint_as_float(fA.z & 0xFFFF0000u) * wA;
            a6 += __uint_as_float(fA.w << 16) * wA;
            a7 += __uint_as_float(fA.w & 0xFFFF0000u) * wA;
        }
        // reduce over the 8 edge slots (lane bits 3..5)
        a0 += __shfl_xor(a0, 8, 64); a0 += __shfl_xor(a0, 16, 64); a0 += __shfl_xor(a0, 32, 64);
        a1 += __shfl_xor(a1, 8, 64); a1 += __shfl_xor(a1, 16, 64); a1 += __shfl_xor(a1, 32, 64);
        a2 += __shfl_xor(a2, 8, 64); a2 += __shfl_xor(a2, 16, 64); a2 += __shfl_xor(a2, 32, 64);
        a3 += __shfl_xor(a3, 8, 64); a3 += __shfl_xor(a3, 16, 64); a3 += __shfl_xor(a3, 32, 64);
        a4 += __shfl_xor(a4, 8, 64); a4 += __shfl_xor(a4, 16, 64); a4 += __shfl_xor(a4, 32, 64);
        a5 += __shfl_xor(a5, 8, 64); a5 += __shfl_xor(a5, 16, 64); a5 += __shfl_xor(a5, 32, 64);
        a6 += __shfl_xor(a6, 8, 64); a6 += __shfl_xor(a6, 16, 64); a6 += __shfl_xor(a6, 32, 64);
        a7 += __shfl_xor(a7, 8, 64); a7 += __shfl_xor(a7, 16, 64); a7 += __shfl_xor(a7, 32, 64);
        if (q8 == 0) {
            f32x4 v0 = {a0 * inv_z, a1 * inv_z, a2 * inv_z, a3 * inv_z};
            f32x4 v1 = {a4 * inv_z, a5 * inv_z, a6 * inv_z, a7 * inv_z};
            *(f32x4*)(rst + (size_t)n * HD + (c8 << 3))     = v0;
            *(f32x4*)(rst + (size_t)n * HD + (c8 << 3) + 4) = v1;
        }
    } else {
        // ---- rare big-degree path: two passes, recompute ----
        const int hA = lane & 3;
        const int eo = lane >> 2;
        const float er_nA = er[n * HEADS + hA];
        const float b0 = ee[hA], b1 = ee[HEADS + hA], b2 = ee[2 * HEADS + hA];
        float zacc = 0.f;
        for (int base = 0; base < deg; base += 16) {
            const int idx = base + eo;
            if (idx < deg) {
                const int2 v = sc_csr[p0 + idx];
                const int ty = v.y >> 21;
                float s = el[v.x * HEADS + hA] + er_nA + ((ty == 0) ? b0 : ((ty == 1) ? b1 : b2));
                s = s > 0.f ? s : NEG_SLOPE * s;
                zacc += __expf(s);
            }
        }
#pragma unroll
        for (int m = 4; m < 64; m <<= 1) zacc += __shfl_xor(zacc, m, 64);
        const int h = lane >> 4;
        const int d = lane & 15;
        // every lane holds z[lane&3]; z[h] lives at lane h
        const float inv_z = __frcp_rn(__shfl(zacc, h, 64));
        const float er_n = er[n * HEADS + h];
        const float g0 = ee[h], g1 = ee[HEADS + h], g2 = ee[2 * HEADS + h];
        float racc = 0.f;
        for (int i = 0; i < deg; ++i) {
            const int2 v = sc_csr[p0 + i];
            const int ty = v.y >> 21;
            float s = el[v.x * HEADS + h] + er_n + ((ty == 0) ? g0 : ((ty == 1) ? g1 : g2));
            s = s > 0.f ? s : NEG_SLOPE * s;
            const float a = __expf(s) * inv_z;
            racc += __bfloat162float(featb[(size_t)v.x * HD + lane]) * a;
            if (d == 0) a_out[((size_t)(v.y & 0x1FFFFF) << 2) + h] = a;
        }
        rst[(size_t)n * HD + lane] = racc;
    }
}

extern "C" void kernel_launch(void* const* d_in, const int* in_sizes, int n_in,
                              void* d_out, int out_size, void* d_ws, size_t ws_size,
                              hipStream_t stream)
{
    const float* x        = (const float*)d_in[0];
    const float* W        = (const float*)d_in[1];
    const float* W_e      = (const float*)d_in[2];
    const float* attn_l   = (const float*)d_in[3];
    const float* attn_r   = (const float*)d_in[4];
    const float* attn_e   = (const float*)d_in[5];
    const float* edge_emb = (const float*)d_in[6];
    const int* src   = (const int*)d_in[7];
    const int* dst   = (const int*)d_in[8];
    const int* etype = (const int*)d_in[9];

    float* out     = (float*)d_out;
    float* rst_out = out;                              // N*H*D
    float* a_out   = out + (size_t)N_NODES * HD;       // E*H

    char* w = (char*)d_ws;
    __hip_bfloat16* featb = (__hip_bfloat16*)w; w += (size_t)N_NODES * HD * 2;   // 12.8 MB
    float* el    = (float*)w;  w += (size_t)N_NODES * HEADS * 4;    //  1.6 MB
    float* er    = (float*)w;  w += (size_t)N_NODES * HEADS * 4;    //  1.6 MB
    float* ee    = (float*)w;  w += 64;
    int*   ptr   = (int*)w;    w += (size_t)(N_NODES + 8) * 4;      //  0.4 MB
    int*   deg   = (int*)w;    w += (size_t)(N_NODES + 8) * 4;      //  0.4 MB
    int*   cnt   = (int*)w;    w += (size_t)(NBUCK + 8) * 4;        //  3.2 KB
    short* WTb   = (short*)w;  w += (size_t)HD * IN_FEATS * 2;      //   16 KB
    int2*  sc_bucket = (int2*)w; w += ((size_t)NBUCK * BCAP + 2048) * 8;  // 16.4 MB
    // total ~33.3 MB

    // 1) W -> bf16^T + zero(cnt)
    wt_prep_kernel<<<(IN_FEATS * HD) / 256, 256, 0, stream>>>(W, WTb, cnt);

    // 2) FUSED: scatter (blocks 0..399) || ee (400) || feat GEMM (401..3525)
    feat_scatter_kernel<<<PBLK + 1 + NFEAT, 256, 0, stream>>>(
        x, WTb, attn_l, attn_r, edge_emb, W_e, attn_e,
        src, dst, etype, featb, el, er, ee, cnt, sc_bucket);

    // 3) CSR finalize in-place
    bucket_csr_kernel<<<NBUCK, 256, 0, stream>>>(sc_bucket, cnt, ptr, deg);

    // 4) aggregation + fused a_out
    agg_kernel<<<N_NODES / 4, 256, 0, stream>>>(
        sc_bucket, ptr, deg, el, er, ee, featb, rst_out, a_out);
}

// Round 12
// 245.843 us; speedup vs baseline: 2.7557x; 1.0152x over previous
//
#include <hip/hip_runtime.h>
#include <hip/hip_bf16.h>

#define N_NODES   100000
#define N_EDGES   1600000
#define N_ETYPES  3
#define IN_FEATS  128
#define HEADS     4
#define OUT_FEATS 16
#define EDGE_FEATS 64
#define HD        64            // HEADS*OUT_FEATS
#define NEG_SLOPE 0.2f
#define MAXD_LDS  128           // agg fast-path max degree (Poisson(16): P(>128)~0)

#define NBUCK     800           // buckets for counting sort
#define NPB       125           // nodes per bucket (800*125 = N_NODES)
#define PBLK      400           // scatter blocks
#define EPB       4000          // edges per scatter block
#define BCAP      2560          // fixed bucket-region capacity (mean 2000, 12.5 sigma)
#define FROWS     32            // rows per feat block (100000/32 = 3125 exact)
#define NFEAT     (N_NODES / FROWS)   // 3125
#define WTROWS    80            // 64 feat cols + 4 el + 4 er + 8 zero-pad

// fused grid: [0,PBLK) scatter | PBLK service(ee) | (PBLK, PBLK+NFEAT] feat
// sc_bucket payload (int2): {src, e | ty<<21 | ld<<23}; after csr: {src, e | ty<<21}

typedef short s16x8 __attribute__((ext_vector_type(8)));
typedef float f32x4 __attribute__((ext_vector_type(4)));

__device__ __forceinline__ short f2bs(float f) {
    __hip_bfloat16 h = __float2bfloat16(f);
    return *reinterpret_cast<short*>(&h);
}

// ---------------------------------------------------------------------------
// Prep: WTb bf16 [80][128]. Rows 0..63: W^T. Rows 64..67: Wl (el cols),
// 68..71: Wr (er cols), 72..79: zero. el/er thus become extra GEMM columns —
// the feat kernel's shuffle epilogue is eliminated. Block 0 zeroes cnt.
// ---------------------------------------------------------------------------
__global__ __launch_bounds__(256) void wt_prep_kernel(
    const float* __restrict__ W,
    const float* __restrict__ attn_l,
    const float* __restrict__ attn_r,
    short* __restrict__ WTb, int* __restrict__ cnt)
{
    const int t = blockIdx.x * 256 + threadIdx.x;   // 0..10239
    const int n = t >> 7, k = t & 127;
    short v;
    if (n < 64) {
        v = f2bs(W[k * HD + n]);
    } else if (n < 72) {
        const int h = (n - 64) & 3;
        const float* av = (n < 68) ? attn_l : attn_r;
        float s = 0.f;
#pragma unroll
        for (int d = 0; d < OUT_FEATS; ++d)
            s += W[k * HD + h * OUT_FEATS + d] * av[h * OUT_FEATS + d];
        v = f2bs(s);
    } else {
        v = 0;
    }
    WTb[n * IN_FEATS + k] = v;
    if (blockIdx.x == 0)
        for (int j = threadIdx.x; j < NBUCK; j += 256) cnt[j] = 0;
}

// ---------------------------------------------------------------------------
// FUSED kernel (320 threads): scatter (blocks < PBLK) runs CONCURRENTLY with
// the MFMA feat GEMM (blocks > PBLK). Block PBLK computes ee.
// Feat path: 5 waves — waves 0..3 produce feat cols, wave 4 produces the
// el/er tile directly from MFMA acc (no cross-lane reduction needed).
// ---------------------------------------------------------------------------
#define XS_STRIDE 136   // 128 + 8 pad shorts
__global__ __launch_bounds__(320) void feat_scatter_kernel(
    const float* __restrict__ x,
    const short* __restrict__ WTb,
    const float* __restrict__ edge_emb,
    const float* __restrict__ W_e,
    const float* __restrict__ attn_e,
    const int* __restrict__ src, const int* __restrict__ dst,
    const int* __restrict__ etype,
    __hip_bfloat16* __restrict__ featb,
    float* __restrict__ el,
    float* __restrict__ er,
    float* __restrict__ ee,
    int* __restrict__ cnt, int2* __restrict__ sc_bucket)
{
    __shared__ __align__(16) char smem[FROWS * XS_STRIDE * 2];   // 8.7 KB union
    const int t = threadIdx.x;
    const int b = blockIdx.x;

    if (b < PBLK) {
        // ---- scatter path: LDS hist -> region claim -> LDS-cursor scatter ----
        int* h = (int*)smem;                 // NBUCK ints (3.2 KB of union)
        int buld[13];                        // ceil(EPB/320) = 13
        for (int j = t; j < NBUCK; j += 320) h[j] = 0;
        __syncthreads();
        const int e0 = b * EPB;
        int k = 0;
        for (int i = t; i < EPB; i += 320, ++k) {
            const int dn = dst[e0 + i];
            const int bu = dn / NPB;
            const int ld = dn - bu * NPB;
            buld[k] = bu | (ld << 16);
            atomicAdd(&h[bu], 1);
        }
        __syncthreads();
        for (int j = t; j < NBUCK; j += 320) {
            const int c = h[j];
            h[j] = j * BCAP + (c ? atomicAdd(&cnt[j], c) : 0);  // region cursor
        }
        __syncthreads();
        k = 0;
        for (int i = t; i < EPB; i += 320, ++k) {
            const int e  = e0 + i;
            const int bu = buld[k] & 0xFFFF;
            const int ld = buld[k] >> 16;
            const int slot = atomicAdd(&h[bu], 1);
            sc_bucket[slot] = make_int2(src[e], e | (etype[e] << 21) | (ld << 23));
        }
        return;
    }

    if (b == PBLK) {
        // ---- service block: ee (12 jobs over 5 waves) ----
        const int wv = t >> 6, e = t & 63;
        for (int j = wv; j < N_ETYPES * HEADS; j += 5) {
            const int ty = j >> 2, h = j & 3;
            float ef = 0.f;
#pragma unroll
            for (int k = 0; k < EDGE_FEATS; ++k)
                ef += edge_emb[ty * EDGE_FEATS + k] *
                      W_e[k * (HEADS * EDGE_FEATS) + h * EDGE_FEATS + e];
            float v = ef * attn_e[h * EDGE_FEATS + e];
#pragma unroll
            for (int m = 1; m < 64; m <<= 1) v += __shfl_xor(v, m, 64);
            if (e == 0) ee[ty * HEADS + h] = v;
        }
        return;
    }

    // ---- feat path: 32 rows/block MFMA GEMM; wave 4 = el/er tile ----
    short* Xs = (short*)smem;                // FROWS*XS_STRIDE shorts
    const int row0 = (b - PBLK - 1) * FROWS;
    if (t < 256) {   // stage x -> bf16 LDS: 16 elems/thread
        const int r = t >> 3, k0 = (t & 7) * 16;
        const float4* xg = (const float4*)(x + (size_t)(row0 + r) * IN_FEATS + k0);
        const float4 v0 = xg[0], v1 = xg[1], v2 = xg[2], v3 = xg[3];
        s16x8 p0, p1;
        p0[0] = f2bs(v0.x); p0[1] = f2bs(v0.y); p0[2] = f2bs(v0.z); p0[3] = f2bs(v0.w);
        p0[4] = f2bs(v1.x); p0[5] = f2bs(v1.y); p0[6] = f2bs(v1.z); p0[7] = f2bs(v1.w);
        p1[0] = f2bs(v2.x); p1[1] = f2bs(v2.y); p1[2] = f2bs(v2.z); p1[3] = f2bs(v2.w);
        p1[4] = f2bs(v3.x); p1[5] = f2bs(v3.y); p1[6] = f2bs(v3.z); p1[7] = f2bs(v3.w);
        *(s16x8*)&Xs[r * XS_STRIDE + k0]     = p0;
        *(s16x8*)&Xs[r * XS_STRIDE + k0 + 8] = p1;
    }

    const int w    = t >> 6;                 // 0..4 (wave 4 = el/er tile)
    const int lane = t & 63;
    const int m    = lane & 15;
    const int q    = lane >> 4;

    // B-fragments direct from WTb (L1-resident 20KB); wave 4 hits rows 64..79
    s16x8 bfr[4];
#pragma unroll
    for (int kb = 0; kb < 4; ++kb)
        bfr[kb] = *(const s16x8*)(WTb + (size_t)(w * 16 + m) * IN_FEATS + kb * 32 + q * 8);

    __syncthreads();

#pragma unroll
    for (int rg = 0; rg < 2; ++rg) {
        f32x4 acc = {0.f, 0.f, 0.f, 0.f};
#pragma unroll
        for (int kb = 0; kb < 4; ++kb) {
            const s16x8 af = *(const s16x8*)&Xs[(rg * 16 + m) * XS_STRIDE + kb * 32 + q * 8];
            acc = __builtin_amdgcn_mfma_f32_16x16x32_bf16(af, bfr[kb], acc, 0, 0, 0);
        }
        if (w < 4) {
#pragma unroll
            for (int r = 0; r < 4; ++r) {
                const int row = row0 + rg * 16 + q * 4 + r;
                featb[(size_t)row * HD + w * 16 + m] = __float2bfloat16(acc[r]);
            }
        } else {
#pragma unroll
            for (int r = 0; r < 4; ++r) {
                const int row = row0 + rg * 16 + q * 4 + r;
                if (m < 4)      el[row * HEADS + m]       = acc[r];
                else if (m < 8) er[row * HEADS + (m - 4)] = acc[r];
            }
        }
    }
}

// ---------------------------------------------------------------------------
// CSR finalize IN-PLACE: one block per bucket; full LDS stage, bin over 125
// local nodes, write back into the SAME fixed region. Emits ptr[n] + deg[n].
// ---------------------------------------------------------------------------
__global__ __launch_bounds__(256) void bucket_csr_kernel(
    int2* __restrict__ sc_bucket, const int* __restrict__ cnt,
    int* __restrict__ ptr, int* __restrict__ deg)
{
    __shared__ int2 sbuf[BCAP];       // 20.5 KB
    __shared__ int sdeg4[4][128];     // per-wave hists, 2 KB
    __shared__ int sdg[128];
    __shared__ int scur[128];
    const int t = threadIdx.x, b = blockIdx.x;
    const int wid = t >> 6;

    sdeg4[0][t & 127] = 0; sdeg4[1][t & 127] = 0;
    if (t < 128) { sdeg4[2][t] = 0; sdeg4[3][t] = 0; }
    __syncthreads();
    const int count = min(cnt[b], BCAP);
    const int base  = b * BCAP;

    for (int i = t; i < count; i += 256) {
        const int2 v = sc_bucket[base + i];
        sbuf[i] = v;
        atomicAdd(&sdeg4[wid][(v.y >> 23) & 0x7F], 1);
    }
    __syncthreads();
    int orig = 0;
    if (t < 128) {
        orig = sdeg4[0][t] + sdeg4[1][t] + sdeg4[2][t] + sdeg4[3][t];
        sdg[t] = orig;
    }
    __syncthreads();
    for (int off = 1; off < 128; off <<= 1) {
        const int v = (t < 128 && t >= off) ? sdg[t - off] : 0;
        __syncthreads();
        if (t < 128) sdg[t] += v;
        __syncthreads();
    }
    if (t < 128) {
        const int excl = sdg[t] - orig;
        if (t < NPB) {
            ptr[b * NPB + t] = base + excl;
            deg[b * NPB + t] = orig;
        }
        scur[t] = base + excl;           // region-local slot base
    }
    __syncthreads();
    for (int i = t; i < count; i += 256) {
        const int2 v = sbuf[i];
        const int ld = (v.y >> 23) & 0x7F;
        const int slot = atomicAdd(&scur[ld], 1);
        sc_bucket[slot] = make_int2(v.x, v.y & 0x7FFFFF);   // {src, e|ty<<21}
    }
}

// ---------------------------------------------------------------------------
// Kernel C: per-dst aggregation + FUSED a_out, one wave per node.
// (byte-identical to round 10 — known-good)
// ---------------------------------------------------------------------------
__global__ __launch_bounds__(256) void agg_kernel(
    const int2* __restrict__ sc_csr, const int* __restrict__ ptr,
    const int* __restrict__ deg_arr,
    const float* __restrict__ el, const float* __restrict__ er,
    const float* __restrict__ ee, const __hip_bfloat16* __restrict__ featb,
    float* __restrict__ rst, float* __restrict__ a_out)
{
    __shared__ float w_lds[4][MAXD_LDS * HEADS];   // 8 KB
    __shared__ int   s_lds[4][MAXD_LDS];           // 2 KB
    __shared__ int   e_lds[4][MAXD_LDS];           // 2 KB
    const int wid  = threadIdx.x >> 6;
    const int lane = threadIdx.x & 63;
    const int n    = blockIdx.x * 4 + wid;

    const int p0  = ptr[n];
    const int deg = deg_arr[n];
    float* wl = w_lds[wid];
    int*   sl = s_lds[wid];
    int*   elds = e_lds[wid];
    const ushort* fb = (const ushort*)featb;

    if (deg <= MAXD_LDS) {
        // ---- phase 1: weights, one lane per (edge, head), 32 edges/iter ----
        const int eo = lane >> 2;          // edge in group of 16
        const int hA = lane & 3;           // head
        const float er_n = er[n * HEADS + hA];
        const float g0 = ee[hA], g1 = ee[HEADS + hA], g2 = ee[2 * HEADS + hA];

        float zacc = 0.f;
        for (int i0 = 0; i0 < deg; i0 += 32) {
            const int idxA = i0 + eo;
            const int idxB = i0 + 16 + eo;
            const bool pA = idxA < deg;
            const bool pB = idxB < deg;
            int2 vA = make_int2(0, 0), vB = make_int2(0, 0);
            if (pA) vA = sc_csr[p0 + idxA];          // both loads issued
            if (pB) vB = sc_csr[p0 + idxB];
            float eA = 0.f, eB = 0.f;
            if (pA) eA = el[vA.x * HEADS + hA];      // both gathers issued
            if (pB) eB = el[vB.x * HEADS + hA];
            if (pA) {
                const int ty = vA.y >> 21;
                float s = eA + er_n + ((ty == 0) ? g0 : ((ty == 1) ? g1 : g2));
                s = s > 0.f ? s : NEG_SLOPE * s;
                const float w = __expf(s);
                wl[idxA * HEADS + hA] = w;
                if (hA == 0) sl[idxA] = vA.x;
                if (hA == 1) elds[idxA] = vA.y & 0x1FFFFF;
                zacc += w;
            }
            if (pB) {
                const int ty = vB.y >> 21;
                float s = eB + er_n + ((ty == 0) ? g0 : ((ty == 1) ? g1 : g2));
                s = s > 0.f ? s : NEG_SLOPE * s;
                const float w = __expf(s);
                wl[idxB * HEADS + hA] = w;
                if (hA == 0) sl[idxB] = vB.x;
                if (hA == 1) elds[idxB] = vB.y & 0x1FFFFF;
                zacc += w;
            }
        }
        // reduce z over edge groups (lane bits 2..5); every lane holds z[lane&3]
        zacc += __shfl_xor(zacc, 4, 64);
        zacc += __shfl_xor(zacc, 8, 64);
        zacc += __shfl_xor(zacc, 16, 64);
        zacc += __shfl_xor(zacc, 32, 64);
        const float izA = (deg > 0) ? __frcp_rn(zacc) : 0.f;

        // ---- a_out epilogue: 4 lanes (heads) write one 16B granule/edge ----
        for (int idx = eo; idx < deg; idx += 16)
            a_out[((size_t)elds[idx] << 2) + hA] = wl[idx * HEADS + hA] * izA;

        // ---- phase 2: accumulate, 16 edges in flight (2 x 8-edge groups) ----
        const int q8 = lane >> 3;          // edge slot 0..7
        const int c8 = lane & 7;           // col group: cols 8*c8 .. 8*c8+7
        const int h8 = c8 >> 1;            // head of those cols
        // z[h8] lives at lane h8
        const float inv_z = (deg > 0) ? __frcp_rn(__shfl(zacc, h8, 64)) : 0.f;

        float a0 = 0.f, a1 = 0.f, a2 = 0.f, a3 = 0.f;
        float a4 = 0.f, a5 = 0.f, a6 = 0.f, a7 = 0.f;
        int i = 0;
        for (; i + 16 <= deg; i += 16) {
            const int idxA = i + q8, idxB = i + 8 + q8;
            const int sA = sl[idxA], sB = sl[idxB];
            const float wA = wl[idxA * HEADS + h8];
            const float wB = wl[idxB * HEADS + h8];
            const uint4 fA = *(const uint4*)(fb + ((size_t)sA << 6) + (c8 << 3));
            const uint4 fB = *(const uint4*)(fb + ((size_t)sB << 6) + (c8 << 3));
            a0 += __uint_as_float(fA.x << 16) * wA;
            a1 += __uint_as_float(fA.x & 0xFFFF0000u) * wA;
            a2 += __uint_as_float(fA.y << 16) * wA;
            a3 += __uint_as_float(fA.y & 0xFFFF0000u) * wA;
            a4 += __uint_as_float(fA.z << 16) * wA;
            a5 += __uint_as_float(fA.z & 0xFFFF0000u) * wA;
            a6 += __uint_as_float(fA.w << 16) * wA;
            a7 += __uint_as_float(fA.w & 0xFFFF0000u) * wA;
            a0 += __uint_as_float(fB.x << 16) * wB;
            a1 += __uint_as_float(fB.x & 0xFFFF0000u) * wB;
            a2 += __uint_as_float(fB.y << 16) * wB;
            a3 += __uint_as_float(fB.y & 0xFFFF0000u) * wB;
            a4 += __uint_as_float(fB.z << 16) * wB;
            a5 += __uint_as_float(fB.z & 0xFFFF0000u) * wB;
            a6 += __uint_as_float(fB.w << 16) * wB;
            a7 += __uint_as_float(fB.w & 0xFFFF0000u) * wB;
        }
        if (i + 8 <= deg) {
            const int idx = i + q8;
            const int sA = sl[idx];
            const float wA = wl[idx * HEADS + h8];
            const uint4 fA = *(const uint4*)(fb + ((size_t)sA << 6) + (c8 << 3));
            a0 += __uint_as_float(fA.x << 16) * wA;
            a1 += __uint_as_float(fA.x & 0xFFFF0000u) * wA;
            a2 += __uint_as_float(fA.y << 16) * wA;
            a3 += __uint_as_float(fA.y & 0xFFFF0000u) * wA;
            a4 += __uint_as_float(fA.z << 16) * wA;
            a5 += __uint_as_float(fA.z & 0xFFFF0000u) * wA;
            a6 += __uint_as_float(fA.w << 16) * wA;
            a7 += __uint_as_float(fA.w & 0xFFFF0000u) * wA;
            i += 8;
        }
        if (i + q8 < deg) {                // tail (<8 edges), one guarded step
            const int idx = i + q8;
            const int sA = sl[idx];
            const float wA = wl[idx * HEADS + h8];
            const uint4 fA = *(const uint4*)(fb + ((size_t)sA << 6) + (c8 << 3));
            a0 += __uint_as_float(fA.x << 16) * wA;
            a1 += __uint_as_float(fA.x & 0xFFFF0000u) * wA;
            a2 += __uint_as_float(fA.y << 16) * wA;
            a3 += __uint_as_float(fA.y & 0xFFFF0000u) * wA;
            a4 += __uint_as_float(fA.z << 16) * wA;
            a5 += __uint_as_float(fA.z & 0xFFFF0000u) * wA;
            a6 += __uint_as_float(fA.w << 16) * wA;
            a7 += __uint_as_float(fA.w & 0xFFFF0000u) * wA;
        }
        // reduce over the 8 edge slots (lane bits 3..5)
        a0 += __shfl_xor(a0, 8, 64); a0 += __shfl_xor(a0, 16, 64); a0 += __shfl_xor(a0, 32, 64);
        a1 += __shfl_xor(a1, 8, 64); a1 += __shfl_xor(a1, 16, 64); a1 += __shfl_xor(a1, 32, 64);
        a2 += __shfl_xor(a2, 8, 64); a2 += __shfl_xor(a2, 16, 64); a2 += __shfl_xor(a2, 32, 64);
        a3 += __shfl_xor(a3, 8, 64); a3 += __shfl_xor(a3, 16, 64); a3 += __shfl_xor(a3, 32, 64);
        a4 += __shfl_xor(a4, 8, 64); a4 += __shfl_xor(a4, 16, 64); a4 += __shfl_xor(a4, 32, 64);
        a5 += __shfl_xor(a5, 8, 64); a5 += __shfl_xor(a5, 16, 64); a5 += __shfl_xor(a5, 32, 64);
        a6 += __shfl_xor(a6, 8, 64); a6 += __shfl_xor(a6, 16, 64); a6 += __shfl_xor(a6, 32, 64);
        a7 += __shfl_xor(a7, 8, 64); a7 += __shfl_xor(a7, 16, 64); a7 += __shfl_xor(a7, 32, 64);
        if (q8 == 0) {
            f32x4 v0 = {a0 * inv_z, a1 * inv_z, a2 * inv_z, a3 * inv_z};
            f32x4 v1 = {a4 * inv_z, a5 * inv_z, a6 * inv_z, a7 * inv_z};
            *(f32x4*)(rst + (size_t)n * HD + (c8 << 3))     = v0;
            *(f32x4*)(rst + (size_t)n * HD + (c8 << 3) + 4) = v1;
        }
    } else {
        // ---- rare big-degree path: two passes, recompute ----
        const int hA = lane & 3;
        const int eo = lane >> 2;
        const float er_nA = er[n * HEADS + hA];
        const float b0 = ee[hA], b1 = ee[HEADS + hA], b2 = ee[2 * HEADS + hA];
        float zacc = 0.f;
        for (int base = 0; base < deg; base += 16) {
            const int idx = base + eo;
            if (idx < deg) {
                const int2 v = sc_csr[p0 + idx];
                const int ty = v.y >> 21;
                float s = el[v.x * HEADS + hA] + er_nA + ((ty == 0) ? b0 : ((ty == 1) ? b1 : b2));
                s = s > 0.f ? s : NEG_SLOPE * s;
                zacc += __expf(s);
            }
        }
#pragma unroll
        for (int m = 4; m < 64; m <<= 1) zacc += __shfl_xor(zacc, m, 64);
        const int h = lane >> 4;
        const int d = lane & 15;
        // every lane holds z[lane&3]; z[h] lives at lane h
        const float inv_z = __frcp_rn(__shfl(zacc, h, 64));
        const float er_n = er[n * HEADS + h];
        const float g0 = ee[h], g1 = ee[HEADS + h], g2 = ee[2 * HEADS + h];
        float racc = 0.f;
        for (int i = 0; i < deg; ++i) {
            const int2 v = sc_csr[p0 + i];
            const int ty = v.y >> 21;
            float s = el[v.x * HEADS + h] + er_n + ((ty == 0) ? g0 : ((ty == 1) ? g1 : g2));
            s = s > 0.f ? s : NEG_SLOPE * s;
            const float a = __expf(s) * inv_z;
            racc += __bfloat162float(featb[(size_t)v.x * HD + lane]) * a;
            if (d == 0) a_out[((size_t)(v.y & 0x1FFFFF) << 2) + h] = a;
        }
        rst[(size_t)n * HD + lane] = racc;
    }
}

extern "C" void kernel_launch(void* const* d_in, const int* in_sizes, int n_in,
                              void* d_out, int out_size, void* d_ws, size_t ws_size,
                              hipStream_t stream)
{
    const float* x        = (const float*)d_in[0];
    const float* W        = (const float*)d_in[1];
    const float* W_e      = (const float*)d_in[2];
    const float* attn_l   = (const float*)d_in[3];
    const float* attn_r   = (const float*)d_in[4];
    const float* attn_e   = (const float*)d_in[5];
    const float* edge_emb = (const float*)d_in[6];
    const int* src   = (const int*)d_in[7];
    const int* dst   = (const int*)d_in[8];
    const int* etype = (const int*)d_in[9];

    float* out     = (float*)d_out;
    float* rst_out = out;                              // N*H*D
    float* a_out   = out + (size_t)N_NODES * HD;       // E*H

    char* w = (char*)d_ws;
    __hip_bfloat16* featb = (__hip_bfloat16*)w; w += (size_t)N_NODES * HD * 2;   // 12.8 MB
    float* el    = (float*)w;  w += (size_t)N_NODES * HEADS * 4;    //  1.6 MB
    float* er    = (float*)w;  w += (size_t)N_NODES * HEADS * 4;    //  1.6 MB
    float* ee    = (float*)w;  w += 64;
    int*   ptr   = (int*)w;    w += (size_t)(N_NODES + 8) * 4;      //  0.4 MB
    int*   deg   = (int*)w;    w += (size_t)(N_NODES + 8) * 4;      //  0.4 MB
    int*   cnt   = (int*)w;    w += (size_t)(NBUCK + 8) * 4;        //  3.2 KB
    short* WTb   = (short*)w;  w += (size_t)WTROWS * IN_FEATS * 2;  //   20 KB
    int2*  sc_bucket = (int2*)w; w += ((size_t)NBUCK * BCAP + 2048) * 8;  // 16.4 MB
    // total ~33.3 MB

    // 1) WTb[80][128] (feat + el/er columns) + zero(cnt)
    wt_prep_kernel<<<(WTROWS * IN_FEATS) / 256, 256, 0, stream>>>(
        W, attn_l, attn_r, WTb, cnt);

    // 2) FUSED: scatter (0..399) || ee (400) || feat GEMM w/ el-er tile (401..)
    feat_scatter_kernel<<<PBLK + 1 + NFEAT, 320, 0, stream>>>(
        x, WTb, edge_emb, W_e, attn_e,
        src, dst, etype, featb, el, er, ee, cnt, sc_bucket);

    // 3) CSR finalize in-place
    bucket_csr_kernel<<<NBUCK, 256, 0, stream>>>(sc_bucket, cnt, ptr, deg);

    // 4) aggregation + fused a_out
    agg_kernel<<<N_NODES / 4, 256, 0, stream>>>(
        sc_bucket, ptr, deg, el, er, ee, featb, rst_out, a_out);
}